// Round 6
// baseline (670.287 us; speedup 1.0000x reference)
//
#include <hip/hip_runtime.h>
#include <hip/hip_bf16.h>

typedef __attribute__((ext_vector_type(8))) __bf16 bf16x8;
typedef __attribute__((ext_vector_type(4))) float f32x4;
typedef __attribute__((ext_vector_type(4))) int i32x4;
typedef __attribute__((ext_vector_type(4))) unsigned short u16x4;

#define MFMA16(a, b, c) __builtin_amdgcn_mfma_f32_16x16x32_bf16((a), (b), (c), 0, 0, 0)

__device__ __forceinline__ void gload_lds16(const void* g, void* l)
{
    __builtin_amdgcn_global_load_lds(
        (const __attribute__((address_space(1))) unsigned int*)g,
        (__attribute__((address_space(3))) unsigned int*)l, 16, 0, 0);
}

// ---------------------------------------------------------------- casts
// embedded (B,1024,1024) fp32 -> premise/hypothesis (8192,1024) bf16 contiguous
__global__ __launch_bounds__(256) void cast_emb_kernel(const float* __restrict__ emb,
                                                       __bf16* __restrict__ Pb,
                                                       __bf16* __restrict__ Hb)
{
    int i = (blockIdx.x * 256 + threadIdx.x) * 4;   // element in (8192,1024) dest space
    int r = i >> 10, d = i & 1023;
    size_t src = ((size_t)(r >> 9) * 1024 + (r & 511)) * 1024 + d;
    f32x4 p = *(const f32x4*)(emb + src);
    f32x4 h = *(const f32x4*)(emb + src + 512 * 1024);
    union { __bf16 b[4]; u16x4 u; } cp, ch;
#pragma unroll
    for (int j = 0; j < 4; ++j) { cp.b[j] = (__bf16)p[j]; ch.b[j] = (__bf16)h[j]; }
    *(u16x4*)(Pb + i) = cp.u;
    *(u16x4*)(Hb + i) = ch.u;
}

// 8 weights W (1024,1024) fp32 row-major -> Wt (1024,1024) bf16, Wt[n][k] = W[k][n]
struct WPtrs { const float* p[8]; };
__global__ __launch_bounds__(256) void cast_wt_kernel(WPtrs wp, __bf16* __restrict__ Wt0)
{
    const float* W = wp.p[blockIdx.z];
    __bf16* Wt = Wt0 + (size_t)blockIdx.z * 1048576;
    __shared__ float tile[32][33];
    int n0 = blockIdx.x * 32, k0 = blockIdx.y * 32;
    int tx = threadIdx.x, ty = threadIdx.y;
#pragma unroll
    for (int i = ty; i < 32; i += 8)
        tile[i][tx] = W[(size_t)(k0 + i) * 1024 + n0 + tx];
    __syncthreads();
#pragma unroll
    for (int i = ty; i < 32; i += 8)
        Wt[(size_t)(n0 + i) * 1024 + k0 + tx] = (__bf16)tile[tx][i];
}

// ---------------------------------------------------------------- GEMM (m97 structure)
// C(M,N) = A(M,K) @ Bt^T + bias.  A,Bt bf16 row-major, Bt is (N,K).
// EPI 0: Cb[row*N+col] = bf16(v)
// EPI 2: Cf[row*N+col] = v + resid  (fp32, resid = embedded slice)
// EPI 3: N=2048 fused K|V: col<1024 -> Cb[row*1024+col] (K, bias);
//        col>=1024 -> Cb2 V-transpose (B,H,64,512), bias2
template <int EPI>
__global__ __launch_bounds__(256, 3) void gemm_bt(const __bf16* __restrict__ A,
                                                  const __bf16* __restrict__ Bt,
                                                  const float* __restrict__ bias,
                                                  const float* __restrict__ bias2,
                                                  __bf16* __restrict__ Cb,
                                                  __bf16* __restrict__ Cb2,
                                                  float* __restrict__ Cf,
                                                  const float* __restrict__ resid,
                                                  int resid_half, int M, int N, int K)
{
    __shared__ __align__(16) __bf16 As[128 * 32];
    __shared__ __align__(16) __bf16 Bs[128 * 32];
    const int t = threadIdx.x;
    const int l = t & 63, w = t >> 6;
    const int wr = w >> 1, wc = w & 1;
    const int lrow = l & 15, lk = l >> 4;
    const int m0 = blockIdx.y * 128, n0 = blockIdx.x * 128;
    const int r0 = t >> 2, kc0 = (t & 3) * 8;

    const __bf16* gA0 = A + (size_t)(m0 + r0) * K + kc0;
    const __bf16* gA1 = gA0 + (size_t)64 * K;
    const __bf16* gB0 = Bt + (size_t)(n0 + r0) * K + kc0;
    const __bf16* gB1 = gB0 + (size_t)64 * K;
    // LDS dests are lane-linear (byte offset == t*16) -> valid global_load_lds targets
    __bf16* dA0 = &As[r0 * 32 + kc0];
    __bf16* dA1 = &As[(r0 + 64) * 32 + kc0];
    __bf16* dB0 = &Bs[r0 * 32 + kc0];
    __bf16* dB1 = &Bs[(r0 + 64) * 32 + kc0];

    const f32x4 zero = {0.f, 0.f, 0.f, 0.f};
    f32x4 acc[4][4];
#pragma unroll
    for (int mi = 0; mi < 4; ++mi)
#pragma unroll
        for (int ni = 0; ni < 4; ++ni) acc[mi][ni] = zero;

    const int nk = K >> 5;
    for (int kt = 0; kt < nk; ++kt) {
        const int ko = kt * 32;
        gload_lds16(gA0 + ko, dA0);
        gload_lds16(gA1 + ko, dA1);
        gload_lds16(gB0 + ko, dB0);
        gload_lds16(gB1 + ko, dB1);
        __syncthreads();   // vmcnt(0) drain before barrier -> LDS ready
        bf16x8 af[4], bfv[4];
#pragma unroll
        for (int mi = 0; mi < 4; ++mi)
            af[mi] = *(const bf16x8*)(&As[(wr * 64 + mi * 16 + lrow) * 32 + lk * 8]);
#pragma unroll
        for (int ni = 0; ni < 4; ++ni)
            bfv[ni] = *(const bf16x8*)(&Bs[(wc * 64 + ni * 16 + lrow) * 32 + lk * 8]);
#pragma unroll
        for (int mi = 0; mi < 4; ++mi)
#pragma unroll
            for (int ni = 0; ni < 4; ++ni)
                acc[mi][ni] = MFMA16(af[mi], bfv[ni], acc[mi][ni]);
        __syncthreads();
    }

#pragma unroll
    for (int mi = 0; mi < 4; ++mi) {
#pragma unroll
        for (int ni = 0; ni < 4; ++ni) {
            int col = n0 + wc * 64 + ni * 16 + lrow;
            float bv = (EPI == 3 && col >= 1024) ? bias2[col - 1024] : bias[col];
#pragma unroll
            for (int r = 0; r < 4; ++r) {
                int row = m0 + wr * 64 + mi * 16 + lk * 4 + r;
                float v = acc[mi][ni][r] + bv;
                if (EPI == 0) {
                    Cb[(size_t)row * N + col] = (__bf16)v;
                } else if (EPI == 3) {
                    if (col < 1024) {
                        Cb[(size_t)row * 1024 + col] = (__bf16)v;
                    } else {
                        int c2 = col - 1024;
                        int b_ = row >> 9, pos = row & 511;
                        int h_ = c2 >> 6, hd = c2 & 63;
                        Cb2[(((size_t)(b_ * 16 + h_) * 64 + hd) << 9) + pos] = (__bf16)v;
                    }
                } else {
                    int b_ = row >> 9, s = row & 511;
                    float rv = resid[((size_t)b_ * 1024 + resid_half + s) * 1024 + col];
                    Cf[(size_t)row * N + col] = v + rv;
                }
            }
        }
    }
}

// ---------------------------------------------------------------- attention
// K-split flash attention, 1-D grid of 2048 with XCD-locality decode:
//   xcd = id&7, slot = id>>3, bh = xcd*32 + (slot>>3), q0 = (slot&7)*64.
// XCD x owns bh [32x,32x+32); the 8 q-block WGs of one bh are consecutive slots
// on one XCD -> temporally co-resident -> K/V dedupe in that XCD's L2
// (resident footprint ~16 bh x 128 KB = 2 MB < 4 MB L2).
// LDS = 32 KB K-tile (reused as P-tile) + mask -> 4 WGs/CU.
// Swapped QK^T (mfma(K,Q)): lane owns softmax row q = w*16+lrow; P rows
// wave-private (same-wave LDS write->read, no barrier).
__global__ __launch_bounds__(256, 4) void attn_kernel(const __bf16* __restrict__ Q,
                                                      const __bf16* __restrict__ Kb,
                                                      const __bf16* __restrict__ Vt,
                                                      const float* __restrict__ mask,
                                                      int mask_half,
                                                      __bf16* __restrict__ att)
{
    __shared__ __align__(16) __bf16 KP[256 * 64];  // 32 KB: K-tile swizzled; then P-tile [64][256]
    __shared__ __align__(16) float msk[512];
    const int id = blockIdx.x;
    const int xcd = id & 7, slot = id >> 3;
    const int bh = xcd * 32 + (slot >> 3);
    const int q0 = (slot & 7) * 64;
    const int b = bh >> 4, h = bh & 15;
    const int t = threadIdx.x, l = t & 63, w = t >> 6;
    const int lrow = l & 15, lk = l >> 4;
    char* KPc = (char*)KP;

    const __bf16* kbase = Kb + ((size_t)b * 512) * 1024 + h * 64;
    const __bf16* vsrc = Vt + (size_t)bh * 64 * 512;

    // stage K tile 0 (pos 0..255): LDS slot s of row pos holds global slot s^(pos&7)
#pragma unroll
    for (int i = 0; i < 8; ++i) {
        int c = t + i * 256;
        int pos = c >> 3, gslot = (c & 7) ^ (pos & 7);
        gload_lds16(kbase + (size_t)pos * 1024 + gslot * 8, KPc + c * 16);
    }
    for (int i = t; i < 512; i += 256) msk[i] = mask[b * 1024 + mask_half + i];

    const int qrow = q0 + w * 16 + lrow;
    const __bf16* qptr = Q + ((size_t)(b * 512 + qrow)) * 1024 + h * 64;
    bf16x8 qf0 = *(const bf16x8*)(qptr + lk * 8);
    bf16x8 qf1 = *(const bf16x8*)(qptr + 32 + lk * 8);

    const f32x4 zero = {0.f, 0.f, 0.f, 0.f};
    f32x4 av[4];
#pragma unroll
    for (int ni = 0; ni < 4; ++ni) av[ni] = zero;
    float m_run = -3e38f, su = 0.f;
    const int psw = lrow & 7;
    char* prowp = KPc + (w * 16 + lrow) * 512;   // P-tile row (512 B = 32 slots)
    f32x4 sc[16];

    auto qk_tile = [&]() {
#pragma unroll
        for (int jj = 0; jj < 16; ++jj) {
            const char* kb = KPc + (jj * 16 + lrow) * 128;
            bf16x8 k0 = *(const bf16x8*)(kb + ((lk ^ psw) << 4));
            bf16x8 k1 = *(const bf16x8*)(kb + (((lk + 4) ^ psw) << 4));
            f32x4 c = zero;
            c = MFMA16(k0, qf0, c);    // swapped: C[row=k local][col=q local]
            c = MFMA16(k1, qf1, c);
            sc[jj] = c;
        }
    };

    auto process_tile = [&](int koff) {
        float mt = -3e38f;
#pragma unroll
        for (int jj = 0; jj < 16; ++jj) {
            f32x4 mv = *(const f32x4*)(&msk[koff + jj * 16 + lk * 4]);
#pragma unroll
            for (int r = 0; r < 4; ++r) {
                float s = sc[jj][r] * 0.125f;   // 1/sqrt(64)
                if (mv[r] == 0.f) s = -1e9f;
                sc[jj][r] = s;
                mt = fmaxf(mt, s);
            }
        }
        mt = fmaxf(mt, __shfl_xor(mt, 16));
        mt = fmaxf(mt, __shfl_xor(mt, 32));
        float m_new = fmaxf(m_run, mt);
        float f = __expf(m_run - m_new);
        float ssum = 0.f;
#pragma unroll
        for (int jj = 0; jj < 16; ++jj)
#pragma unroll
            for (int r = 0; r < 4; ++r) {
                float e = __expf(sc[jj][r] - m_new);
                sc[jj][r] = e;
                ssum += e;
            }
        ssum += __shfl_xor(ssum, 16);
        ssum += __shfl_xor(ssum, 32);
        su = su * f + ssum;
        m_run = m_new;
        // av rows live at q-local = lk*4+r; rescale factor is lane lrow = lk*4+r's f
#pragma unroll
        for (int r = 0; r < 4; ++r) {
            float fr = __shfl(f, (l & 48) | (lk * 4 + r));
#pragma unroll
            for (int ni = 0; ni < 4; ++ni) av[ni][r] *= fr;
        }
    };

    auto pv_tile = [&](int koff) {
        // P write: wave-private rows, packed b64, swizzled slots
#pragma unroll
        for (int jj = 0; jj < 16; ++jj) {
            union { __bf16 b[4]; unsigned long long u; } pk;
#pragma unroll
            for (int r = 0; r < 4; ++r) pk.b[r] = (__bf16)sc[jj][r];
            int slot2 = jj * 2 + (lk >> 1);
            *(unsigned long long*)(prowp + (((slot2 ^ psw) << 4) | ((lk & 1) << 3))) = pk.u;
        }
#pragma unroll
        for (int ks = 0; ks < 8; ++ks) {
            bf16x8 pf = *(const bf16x8*)(prowp + (((ks * 4 + lk) ^ psw) << 4));
#pragma unroll
            for (int ni = 0; ni < 4; ++ni) {
                bf16x8 vf = *(const bf16x8*)(&vsrc[(ni * 16 + lrow) * 512 + koff + ks * 32 + lk * 8]);
                av[ni] = MFMA16(pf, vf, av[ni]);
            }
        }
    };

    __syncthreads();        // K0 staged (vmcnt drained before barrier)
    qk_tile();
    process_tile(0);
    __syncthreads();        // all waves done reading K0 -> P may overwrite
    pv_tile(0);
    __syncthreads();        // all P0 reads done -> restage
#pragma unroll
    for (int i = 0; i < 8; ++i) {
        int c = t + i * 256;
        int pos = c >> 3, gslot = (c & 7) ^ (pos & 7);
        gload_lds16(kbase + (size_t)(256 + pos) * 1024 + gslot * 8, KPc + c * 16);
    }
    __syncthreads();        // K1 staged
    qk_tile();
    process_tile(256);
    __syncthreads();        // all waves done reading K1
    pv_tile(256);

    const float inv = 1.f / su;
#pragma unroll
    for (int r = 0; r < 4; ++r) {
        float ivr = __shfl(inv, (l & 48) | (lk * 4 + r));
        int qq = q0 + w * 16 + lk * 4 + r;
#pragma unroll
        for (int ni = 0; ni < 4; ++ni)
            att[((size_t)(b * 512 + qq)) * 1024 + h * 64 + ni * 16 + lrow] =
                (__bf16)(av[ni][r] * ivr);
    }
}

// ---------------------------------------------------------------- layernorm (row of 1024)
__global__ __launch_bounds__(256) void ln_kernel(const float* __restrict__ X,
                                                 const float* __restrict__ g,
                                                 const float* __restrict__ bta,
                                                 __bf16* __restrict__ out)
{
    const int r = blockIdx.x, t = threadIdx.x;
    const float* x = X + (size_t)r * 1024;
    f32x4 v = *(const f32x4*)(x + t * 4);
    float s = v[0] + v[1] + v[2] + v[3];
    float q = v[0] * v[0] + v[1] * v[1] + v[2] * v[2] + v[3] * v[3];
#pragma unroll
    for (int d = 1; d < 64; d <<= 1) { s += __shfl_xor(s, d); q += __shfl_xor(q, d); }
    __shared__ float rs[4], rq[4];
    if ((t & 63) == 0) { rs[t >> 6] = s; rq[t >> 6] = q; }
    __syncthreads();
    s = rs[0] + rs[1] + rs[2] + rs[3];
    q = rq[0] + rq[1] + rq[2] + rq[3];
    float mu = s * (1.f / 1024.f);
    float var = q * (1.f / 1024.f) - mu * mu;
    float rstd = rsqrtf(var + 1e-5f);
#pragma unroll
    for (int j = 0; j < 4; ++j) {
        int c = t * 4 + j;
        out[(size_t)r * 1024 + c] = (__bf16)((v[j] - mu) * rstd * g[c] + bta[c]);
    }
}

// ---------------------------------------------------------------- pools
// z selects half: emb rows [z*512, z*512+512) -> feats[b][z*1024 + d]
__global__ __launch_bounds__(256) void pool_f32_kernel(const float* __restrict__ X,
                                                       const float* __restrict__ mask,
                                                       float* __restrict__ feats)
{
    const int b = blockIdx.y, d0 = blockIdx.x * 64, half = blockIdx.z * 512;
    const int t = threadIdx.x, d = d0 + (t & 63), sl = t >> 6;
    float acc = 0.f, ms = 0.f;
#pragma unroll 4
    for (int s = sl * 128; s < sl * 128 + 128; ++s) {
        float m = mask[b * 1024 + half + s];
        acc += X[((size_t)b * 1024 + half + s) * 1024 + d] * m;
        ms += m;
    }
    __shared__ float ra[4][64];
    __shared__ float rm[4];
    ra[sl][t & 63] = acc;
    if ((t & 63) == 0) rm[sl] = ms;
    __syncthreads();
    if (t < 64) {
        float a = ra[0][t] + ra[1][t] + ra[2][t] + ra[3][t];
        float m = rm[0] + rm[1] + rm[2] + rm[3];
        feats[b * 4096 + blockIdx.z * 1024 + d0 + t] = a / fmaxf(m, 1e-9f);
    }
}

__global__ __launch_bounds__(256) void pool_bf16_kernel(const __bf16* __restrict__ X,
                                                        const float* __restrict__ mask,
                                                        int half, float* __restrict__ feats,
                                                        int off)
{
    const int b = blockIdx.y, d0 = blockIdx.x * 64;
    const int t = threadIdx.x, d = d0 + (t & 63), sl = t >> 6;
    float acc = 0.f, ms = 0.f;
#pragma unroll 4
    for (int s = sl * 128; s < sl * 128 + 128; ++s) {
        float m = mask[b * 1024 + half + s];
        acc += (float)X[((size_t)b * 512 + s) * 1024 + d] * m;
        ms += m;
    }
    __shared__ float ra[4][64];
    __shared__ float rm[4];
    ra[sl][t & 63] = acc;
    if ((t & 63) == 0) rm[sl] = ms;
    __syncthreads();
    if (t < 64) {
        float a = ra[0][t] + ra[1][t] + ra[2][t] + ra[3][t];
        float m = rm[0] + rm[1] + rm[2] + rm[3];
        feats[b * 4096 + off + d0 + t] = a / fmaxf(m, 1e-9f);
    }
}

// ---------------------------------------------------------------- small fp32 MLP
__global__ __launch_bounds__(256) void fc_init_kernel(const float* __restrict__ b1,
                                                      const float* __restrict__ b2,
                                                      float* __restrict__ h1,
                                                      float* __restrict__ h2)
{
    int i = blockIdx.x * 256 + threadIdx.x;
    if (i < 16 * 1024) h1[i] = b1[i & 1023];
    else h2[i - 16 * 1024] = b2[(i - 16 * 1024) & 511];
}

template <int CH, int RELU_IN>
__global__ __launch_bounds__(256) void fc_atomic_kernel(const float* __restrict__ in,
                                                        const float* __restrict__ W,
                                                        float* __restrict__ out,
                                                        int IF, int OF)
{
    __shared__ float ins[16 * CH];
    const int t = threadIdx.x;
    const int col = blockIdx.x * 256 + t;
    const int i0 = blockIdx.y * CH;
#pragma unroll
    for (int idx = t; idx < 16 * CH; idx += 256) {
        int b = idx / CH, i = idx % CH;
        float v = in[b * IF + i0 + i];
        if (RELU_IN) v = fmaxf(v, 0.f);
        ins[idx] = v;
    }
    __syncthreads();
    float acc[16];
#pragma unroll
    for (int b = 0; b < 16; ++b) acc[b] = 0.f;
#pragma unroll 4
    for (int i = 0; i < CH; ++i) {
        float wv = W[(size_t)(i0 + i) * OF + col];
#pragma unroll
        for (int b = 0; b < 16; ++b) acc[b] += ins[b * CH + i] * wv;
    }
#pragma unroll
    for (int b = 0; b < 16; ++b) atomicAdd(out + b * OF + col, acc[b]);
}

__global__ __launch_bounds__(64) void mlp3_kernel(const float* __restrict__ h2,
                                                  const float* __restrict__ W3,
                                                  const float* __restrict__ b3,
                                                  float* __restrict__ out)
{
    int b = blockIdx.x, t = threadIdx.x;
    float a0 = 0.f, a1 = 0.f, a2 = 0.f;
    for (int i = t; i < 512; i += 64) {
        float hv = fmaxf(h2[b * 512 + i], 0.f);
        a0 += hv * W3[i * 3 + 0];
        a1 += hv * W3[i * 3 + 1];
        a2 += hv * W3[i * 3 + 2];
    }
#pragma unroll
    for (int d = 1; d < 64; d <<= 1) {
        a0 += __shfl_xor(a0, d);
        a1 += __shfl_xor(a1, d);
        a2 += __shfl_xor(a2, d);
    }
    if (t == 0) {
        out[b * 3 + 0] = a0 + b3[0];
        out[b * 3 + 1] = a1 + b3[1];
        out[b * 3 + 2] = a2 + b3[2];
    }
}

// ---------------------------------------------------------------- launch
extern "C" void kernel_launch(void* const* d_in, const int* in_sizes, int n_in,
                              void* d_out, int out_size, void* d_ws, size_t ws_size,
                              hipStream_t stream)
{
    const float* emb  = (const float*)d_in[0];
    const float* mask = (const float*)d_in[1];
    const float* W1 = (const float*)d_in[22];
    const float* b1 = (const float*)d_in[23];
    const float* W2 = (const float*)d_in[24];
    const float* b2 = (const float*)d_in[25];
    const float* W3 = (const float*)d_in[26];
    const float* b3 = (const float*)d_in[27];

    char* ws = (char*)d_ws;
    constexpr size_t MB = 1ull << 20;
    __bf16* Pb    = (__bf16*)(ws);                 // 16 MB (8192,1024) bf16
    __bf16* Hb    = (__bf16*)(ws + 16 * MB);       // 16 MB
    __bf16* Wt    = (__bf16*)(ws + 32 * MB);       // 16 MB: 8 x (1024,1024) bf16 W^T
    __bf16* Qb    = (__bf16*)(ws + 48 * MB);       // 16 MB
    __bf16* Kb    = (__bf16*)(ws + 64 * MB);       // 16 MB
    __bf16* Vt    = (__bf16*)(ws + 80 * MB);       // 16 MB (B,H,64,512)
    __bf16* attb  = (__bf16*)(ws + 96 * MB);       // 16 MB
    float*  Of    = (float*) (ws + 48 * MB);       // 32 MB, aliases Qb+Kb (dead by then)
    __bf16* ctx   = (__bf16*)(ws + 112 * MB);      // 16 MB
    float*  feats = (float*) (ws + 128 * MB);      // 256 KB (16,4096)
    float*  h1    = (float*) (ws + 128 * MB + 512 * 1024);  // 64 KB
    float*  h2    = (float*) (ws + 129 * MB);      // 32 KB

    cast_emb_kernel<<<8192, 256, 0, stream>>>(emb, Pb, Hb);
    WPtrs wp;
    const int widx[8] = {2, 4, 6, 8, 12, 14, 16, 18};   // p2h Wq,Wk,Wv,Wo then h2p
    for (int i = 0; i < 8; ++i) wp.p[i] = (const float*)d_in[widx[i]];
    cast_wt_kernel<<<dim3(32, 32, 8), dim3(32, 8), 0, stream>>>(wp, Wt);

    dim3 gg(8, 64);     // (N/128, M/128) for N=1024
    dim3 gkv(16, 64);   // N=2048 fused K|V
    for (int dir = 0; dir < 2; ++dir) {
        const __bf16* qin  = dir ? Hb : Pb;
        const __bf16* kvin = dir ? Pb : Hb;
        const int base = dir ? 12 : 2;
        const __bf16* wq  = Wt + (size_t)(dir * 4 + 0) * 1048576;
        const __bf16* wkv = Wt + (size_t)(dir * 4 + 1) * 1048576;  // Wk|Wv contiguous
        const __bf16* wo  = Wt + (size_t)(dir * 4 + 3) * 1048576;
        const float* bq  = (const float*)d_in[base + 1];
        const float* bk  = (const float*)d_in[base + 3];
        const float* bv  = (const float*)d_in[base + 5];
        const float* bo  = (const float*)d_in[base + 7];
        const float* lng = (const float*)d_in[base + 8];
        const float* lnb = (const float*)d_in[base + 9];
        const int kvhalf  = dir ? 0 : 512;    // p2h attends hypothesis (mask half 512)
        const int reshalf = dir ? 512 : 0;    // residual = q_in slice of embedded

        gemm_bt<0><<<gg, 256, 0, stream>>>(qin, wq, bq, nullptr, Qb, nullptr,
                                           nullptr, nullptr, 0, 8192, 1024, 1024);
        gemm_bt<3><<<gkv, 256, 0, stream>>>(kvin, wkv, bk, bv, Kb, Vt,
                                            nullptr, nullptr, 0, 8192, 2048, 1024);
        attn_kernel<<<2048, 256, 0, stream>>>(Qb, Kb, Vt, mask, kvhalf, attb);
        gemm_bt<2><<<gg, 256, 0, stream>>>(attb, wo, bo, nullptr, nullptr, nullptr,
                                           Of, emb, reshalf, 8192, 1024, 1024);
        ln_kernel<<<8192, 256, 0, stream>>>(Of, lng, lnb, ctx);
        pool_bf16_kernel<<<dim3(16, 16), 256, 0, stream>>>(ctx, mask, dir ? 512 : 0,
                                                           feats, 2048 + dir * 1024);
    }
    pool_f32_kernel<<<dim3(16, 16, 2), 256, 0, stream>>>(emb, mask, feats);

    fc_init_kernel<<<96, 256, 0, stream>>>(b1, b2, h1, h2);
    fc_atomic_kernel<128, 0><<<dim3(4, 32), 256, 0, stream>>>(feats, W1, h1, 4096, 1024);
    fc_atomic_kernel<32, 1><<<dim3(2, 32), 256, 0, stream>>>(h1, W2, h2, 1024, 512);
    mlp3_kernel<<<16, 64, 0, stream>>>(h2, W3, b3, (float*)d_out);
}

// Round 8
// 605.192 us; speedup vs baseline: 1.1076x; 1.1076x over previous
//
#include <hip/hip_runtime.h>
#include <hip/hip_bf16.h>

typedef __attribute__((ext_vector_type(8))) __bf16 bf16x8;
typedef __attribute__((ext_vector_type(4))) float f32x4;
typedef __attribute__((ext_vector_type(4))) int i32x4;
typedef __attribute__((ext_vector_type(4))) unsigned short u16x4;

#define MFMA16(a, b, c) __builtin_amdgcn_mfma_f32_16x16x32_bf16((a), (b), (c), 0, 0, 0)

__device__ __forceinline__ void gload_lds16(const void* g, void* l)
{
    __builtin_amdgcn_global_load_lds(
        (const __attribute__((address_space(1))) unsigned int*)g,
        (__attribute__((address_space(3))) unsigned int*)l, 16, 0, 0);
}

// ---------------------------------------------------------------- casts
// embedded (B,1024,1024) fp32 -> premise/hypothesis (8192,1024) bf16 contiguous
__global__ __launch_bounds__(256) void cast_emb_kernel(const float* __restrict__ emb,
                                                       __bf16* __restrict__ Pb,
                                                       __bf16* __restrict__ Hb)
{
    int i = (blockIdx.x * 256 + threadIdx.x) * 4;   // element in (8192,1024) dest space
    int r = i >> 10, d = i & 1023;
    size_t src = ((size_t)(r >> 9) * 1024 + (r & 511)) * 1024 + d;
    f32x4 p = *(const f32x4*)(emb + src);
    f32x4 h = *(const f32x4*)(emb + src + 512 * 1024);
    union { __bf16 b[4]; u16x4 u; } cp, ch;
#pragma unroll
    for (int j = 0; j < 4; ++j) { cp.b[j] = (__bf16)p[j]; ch.b[j] = (__bf16)h[j]; }
    *(u16x4*)(Pb + i) = cp.u;
    *(u16x4*)(Hb + i) = ch.u;
}

// 8 weights W (1024,1024) fp32 row-major -> Wt (1024,1024) bf16, Wt[n][k] = W[k][n]
struct WPtrs { const float* p[8]; };
__global__ __launch_bounds__(256) void cast_wt_kernel(WPtrs wp, __bf16* __restrict__ Wt0)
{
    const float* W = wp.p[blockIdx.z];
    __bf16* Wt = Wt0 + (size_t)blockIdx.z * 1048576;
    __shared__ float tile[32][33];
    int n0 = blockIdx.x * 32, k0 = blockIdx.y * 32;
    int tx = threadIdx.x, ty = threadIdx.y;
#pragma unroll
    for (int i = ty; i < 32; i += 8)
        tile[i][tx] = W[(size_t)(k0 + i) * 1024 + n0 + tx];
    __syncthreads();
#pragma unroll
    for (int i = ty; i < 32; i += 8)
        Wt[(size_t)(n0 + i) * 1024 + k0 + tx] = (__bf16)tile[tx][i];
}

// ---------------------------------------------------------------- GEMM (m97 structure)
// C(M,N) = A(M,K) @ Bt^T + bias.  A,Bt bf16 row-major, Bt is (N,K).
// EPI 0: Cb[row*N+col] = bf16(v)
// EPI 2: Cf[row*N+col] = v + resid  (fp32, resid = embedded slice)
// EPI 3: N=2048 fused K|V: col<1024 -> Cb[row*1024+col] (K, bias);
//        col>=1024 -> Cb2 V-transpose (B,H,64,512), bias2
template <int EPI>
__global__ __launch_bounds__(256, 3) void gemm_bt(const __bf16* __restrict__ A,
                                                  const __bf16* __restrict__ Bt,
                                                  const float* __restrict__ bias,
                                                  const float* __restrict__ bias2,
                                                  __bf16* __restrict__ Cb,
                                                  __bf16* __restrict__ Cb2,
                                                  float* __restrict__ Cf,
                                                  const float* __restrict__ resid,
                                                  int resid_half, int M, int N, int K)
{
    __shared__ __align__(16) __bf16 As[128 * 32];
    __shared__ __align__(16) __bf16 Bs[128 * 32];
    const int t = threadIdx.x;
    const int l = t & 63, w = t >> 6;
    const int wr = w >> 1, wc = w & 1;
    const int lrow = l & 15, lk = l >> 4;
    const int m0 = blockIdx.y * 128, n0 = blockIdx.x * 128;
    const int r0 = t >> 2, kc0 = (t & 3) * 8;

    const __bf16* gA0 = A + (size_t)(m0 + r0) * K + kc0;
    const __bf16* gA1 = gA0 + (size_t)64 * K;
    const __bf16* gB0 = Bt + (size_t)(n0 + r0) * K + kc0;
    const __bf16* gB1 = gB0 + (size_t)64 * K;
    // LDS dests are lane-linear (byte offset == t*16) -> valid global_load_lds targets
    __bf16* dA0 = &As[r0 * 32 + kc0];
    __bf16* dA1 = &As[(r0 + 64) * 32 + kc0];
    __bf16* dB0 = &Bs[r0 * 32 + kc0];
    __bf16* dB1 = &Bs[(r0 + 64) * 32 + kc0];

    const f32x4 zero = {0.f, 0.f, 0.f, 0.f};
    f32x4 acc[4][4];
#pragma unroll
    for (int mi = 0; mi < 4; ++mi)
#pragma unroll
        for (int ni = 0; ni < 4; ++ni) acc[mi][ni] = zero;

    const int nk = K >> 5;
    for (int kt = 0; kt < nk; ++kt) {
        const int ko = kt * 32;
        gload_lds16(gA0 + ko, dA0);
        gload_lds16(gA1 + ko, dA1);
        gload_lds16(gB0 + ko, dB0);
        gload_lds16(gB1 + ko, dB1);
        __syncthreads();   // vmcnt(0) drain before barrier -> LDS ready
        bf16x8 af[4], bfv[4];
#pragma unroll
        for (int mi = 0; mi < 4; ++mi)
            af[mi] = *(const bf16x8*)(&As[(wr * 64 + mi * 16 + lrow) * 32 + lk * 8]);
#pragma unroll
        for (int ni = 0; ni < 4; ++ni)
            bfv[ni] = *(const bf16x8*)(&Bs[(wc * 64 + ni * 16 + lrow) * 32 + lk * 8]);
#pragma unroll
        for (int mi = 0; mi < 4; ++mi)
#pragma unroll
            for (int ni = 0; ni < 4; ++ni)
                acc[mi][ni] = MFMA16(af[mi], bfv[ni], acc[mi][ni]);
        __syncthreads();
    }

#pragma unroll
    for (int mi = 0; mi < 4; ++mi) {
#pragma unroll
        for (int ni = 0; ni < 4; ++ni) {
            int col = n0 + wc * 64 + ni * 16 + lrow;
            float bv = (EPI == 3 && col >= 1024) ? bias2[col - 1024] : bias[col];
#pragma unroll
            for (int r = 0; r < 4; ++r) {
                int row = m0 + wr * 64 + mi * 16 + lk * 4 + r;
                float v = acc[mi][ni][r] + bv;
                if (EPI == 0) {
                    Cb[(size_t)row * N + col] = (__bf16)v;
                } else if (EPI == 3) {
                    if (col < 1024) {
                        Cb[(size_t)row * 1024 + col] = (__bf16)v;
                    } else {
                        int c2 = col - 1024;
                        int b_ = row >> 9, pos = row & 511;
                        int h_ = c2 >> 6, hd = c2 & 63;
                        Cb2[(((size_t)(b_ * 16 + h_) * 64 + hd) << 9) + pos] = (__bf16)v;
                    }
                } else {
                    int b_ = row >> 9, s = row & 511;
                    float rv = resid[((size_t)b_ * 1024 + resid_half + s) * 1024 + col];
                    Cf[(size_t)row * N + col] = v + rv;
                }
            }
        }
    }
}

// ---------------------------------------------------------------- attention
// K-split flash attention. One WG per (bh, 64-q block); K/V in two 256-pos
// tiles with online softmax. LDS = 32 KB K-tile (reused as P-tile) + mask.
// __launch_bounds__(256,3): VGPR cap ~170 -> sc[16] (64 VGPRs) stays in
// registers. [(256,4) capped VGPR at 64 -> sc spilled to scratch -> ~150 MB
// phantom HBM traffic; the R5/R6 regression. Occupancy here is VGPR-bound
// at 3 WG/CU, which beats spilling.]
// Swapped QK^T (mfma(K,Q)): lane owns softmax row q = w*16+lrow; P rows
// wave-private (same-wave LDS write->read, no barrier before PV).
__global__ __launch_bounds__(256, 3) void attn_kernel(const __bf16* __restrict__ Q,
                                                      const __bf16* __restrict__ Kb,
                                                      const __bf16* __restrict__ Vt,
                                                      const float* __restrict__ mask,
                                                      int mask_half,
                                                      __bf16* __restrict__ att)
{
    __shared__ __align__(16) __bf16 KP[256 * 64];  // 32 KB: K-tile swizzled; then P-tile [64][256]
    __shared__ __align__(16) float msk[512];
    const int bh = blockIdx.x, b = bh >> 4, h = bh & 15;
    const int q0 = blockIdx.y * 64;
    const int t = threadIdx.x, l = t & 63, w = t >> 6;
    const int lrow = l & 15, lk = l >> 4;
    char* KPc = (char*)KP;

    const __bf16* kbase = Kb + ((size_t)b * 512) * 1024 + h * 64;
    const __bf16* vsrc = Vt + (size_t)bh * 64 * 512;

    // stage K tile 0 (pos 0..255): LDS slot s of row pos holds global slot s^(pos&7)
#pragma unroll
    for (int i = 0; i < 8; ++i) {
        int c = t + i * 256;
        int pos = c >> 3, gslot = (c & 7) ^ (pos & 7);
        gload_lds16(kbase + (size_t)pos * 1024 + gslot * 8, KPc + c * 16);
    }
    for (int i = t; i < 512; i += 256) msk[i] = mask[b * 1024 + mask_half + i];

    const int qrow = q0 + w * 16 + lrow;
    const __bf16* qptr = Q + ((size_t)(b * 512 + qrow)) * 1024 + h * 64;
    bf16x8 qf0 = *(const bf16x8*)(qptr + lk * 8);
    bf16x8 qf1 = *(const bf16x8*)(qptr + 32 + lk * 8);

    const f32x4 zero = {0.f, 0.f, 0.f, 0.f};
    f32x4 av[4];
#pragma unroll
    for (int ni = 0; ni < 4; ++ni) av[ni] = zero;
    float m_run = -3e38f, su = 0.f;
    const int psw = lrow & 7;
    char* prowp = KPc + (w * 16 + lrow) * 512;   // P-tile row (512 B = 32 slots)
    f32x4 sc[16];

    auto qk_tile = [&]() {
#pragma unroll
        for (int jj = 0; jj < 16; ++jj) {
            const char* kb = KPc + (jj * 16 + lrow) * 128;
            bf16x8 k0 = *(const bf16x8*)(kb + ((lk ^ psw) << 4));
            bf16x8 k1 = *(const bf16x8*)(kb + (((lk + 4) ^ psw) << 4));
            f32x4 c = zero;
            c = MFMA16(k0, qf0, c);    // swapped: C[row=k local][col=q local]
            c = MFMA16(k1, qf1, c);
            sc[jj] = c;
        }
    };

    auto process_tile = [&](int koff) {
        float mt = -3e38f;
#pragma unroll
        for (int jj = 0; jj < 16; ++jj) {
            f32x4 mv = *(const f32x4*)(&msk[koff + jj * 16 + lk * 4]);
#pragma unroll
            for (int r = 0; r < 4; ++r) {
                float s = sc[jj][r] * 0.125f;   // 1/sqrt(64)
                if (mv[r] == 0.f) s = -1e9f;
                sc[jj][r] = s;
                mt = fmaxf(mt, s);
            }
        }
        mt = fmaxf(mt, __shfl_xor(mt, 16));
        mt = fmaxf(mt, __shfl_xor(mt, 32));
        float m_new = fmaxf(m_run, mt);
        float f = __expf(m_run - m_new);
        float ssum = 0.f;
#pragma unroll
        for (int jj = 0; jj < 16; ++jj)
#pragma unroll
            for (int r = 0; r < 4; ++r) {
                float e = __expf(sc[jj][r] - m_new);
                sc[jj][r] = e;
                ssum += e;
            }
        ssum += __shfl_xor(ssum, 16);
        ssum += __shfl_xor(ssum, 32);
        su = su * f + ssum;
        m_run = m_new;
        // av rows live at q-local = lk*4+r; rescale factor is lane lrow = lk*4+r's f
#pragma unroll
        for (int r = 0; r < 4; ++r) {
            float fr = __shfl(f, (l & 48) | (lk * 4 + r));
#pragma unroll
            for (int ni = 0; ni < 4; ++ni) av[ni][r] *= fr;
        }
    };

    auto pv_tile = [&](int koff) {
        // P write: wave-private rows, packed b64, swizzled slots
#pragma unroll
        for (int jj = 0; jj < 16; ++jj) {
            union { __bf16 b[4]; unsigned long long u; } pk;
#pragma unroll
            for (int r = 0; r < 4; ++r) pk.b[r] = (__bf16)sc[jj][r];
            int slot2 = jj * 2 + (lk >> 1);
            *(unsigned long long*)(prowp + (((slot2 ^ psw) << 4) | ((lk & 1) << 3))) = pk.u;
        }
#pragma unroll
        for (int ks = 0; ks < 8; ++ks) {
            bf16x8 pf = *(const bf16x8*)(prowp + (((ks * 4 + lk) ^ psw) << 4));
#pragma unroll
            for (int ni = 0; ni < 4; ++ni) {
                bf16x8 vf = *(const bf16x8*)(&vsrc[(ni * 16 + lrow) * 512 + koff + ks * 32 + lk * 8]);
                av[ni] = MFMA16(pf, vf, av[ni]);
            }
        }
    };

    __syncthreads();        // K0 staged (vmcnt drained before barrier)
    qk_tile();
    process_tile(0);
    __syncthreads();        // all waves done reading K0 -> P may overwrite
    pv_tile(0);
    __syncthreads();        // all P0 reads done -> restage
#pragma unroll
    for (int i = 0; i < 8; ++i) {
        int c = t + i * 256;
        int pos = c >> 3, gslot = (c & 7) ^ (pos & 7);
        gload_lds16(kbase + (size_t)(256 + pos) * 1024 + gslot * 8, KPc + c * 16);
    }
    __syncthreads();        // K1 staged
    qk_tile();
    process_tile(256);
    __syncthreads();        // all waves done reading K1
    pv_tile(256);

    const float inv = 1.f / su;
#pragma unroll
    for (int r = 0; r < 4; ++r) {
        float ivr = __shfl(inv, (l & 48) | (lk * 4 + r));
        int qq = q0 + w * 16 + lk * 4 + r;
#pragma unroll
        for (int ni = 0; ni < 4; ++ni)
            att[((size_t)(b * 512 + qq)) * 1024 + h * 64 + ni * 16 + lrow] =
                (__bf16)(av[ni][r] * ivr);
    }
}

// ---------------------------------------------------------------- layernorm (row of 1024)
__global__ __launch_bounds__(256) void ln_kernel(const float* __restrict__ X,
                                                 const float* __restrict__ g,
                                                 const float* __restrict__ bta,
                                                 __bf16* __restrict__ out)
{
    const int r = blockIdx.x, t = threadIdx.x;
    const float* x = X + (size_t)r * 1024;
    f32x4 v = *(const f32x4*)(x + t * 4);
    float s = v[0] + v[1] + v[2] + v[3];
    float q = v[0] * v[0] + v[1] * v[1] + v[2] * v[2] + v[3] * v[3];
#pragma unroll
    for (int d = 1; d < 64; d <<= 1) { s += __shfl_xor(s, d); q += __shfl_xor(q, d); }
    __shared__ float rs[4], rq[4];
    if ((t & 63) == 0) { rs[t >> 6] = s; rq[t >> 6] = q; }
    __syncthreads();
    s = rs[0] + rs[1] + rs[2] + rs[3];
    q = rq[0] + rq[1] + rq[2] + rq[3];
    float mu = s * (1.f / 1024.f);
    float var = q * (1.f / 1024.f) - mu * mu;
    float rstd = rsqrtf(var + 1e-5f);
#pragma unroll
    for (int j = 0; j < 4; ++j) {
        int c = t * 4 + j;
        out[(size_t)r * 1024 + c] = (__bf16)((v[j] - mu) * rstd * g[c] + bta[c]);
    }
}

// ---------------------------------------------------------------- pools
// z selects half: emb rows [z*512, z*512+512) -> feats[b][z*1024 + d]
__global__ __launch_bounds__(256) void pool_f32_kernel(const float* __restrict__ X,
                                                       const float* __restrict__ mask,
                                                       float* __restrict__ feats)
{
    const int b = blockIdx.y, d0 = blockIdx.x * 64, half = blockIdx.z * 512;
    const int t = threadIdx.x, d = d0 + (t & 63), sl = t >> 6;
    float acc = 0.f, ms = 0.f;
#pragma unroll 4
    for (int s = sl * 128; s < sl * 128 + 128; ++s) {
        float m = mask[b * 1024 + half + s];
        acc += X[((size_t)b * 1024 + half + s) * 1024 + d] * m;
        ms += m;
    }
    __shared__ float ra[4][64];
    __shared__ float rm[4];
    ra[sl][t & 63] = acc;
    if ((t & 63) == 0) rm[sl] = ms;
    __syncthreads();
    if (t < 64) {
        float a = ra[0][t] + ra[1][t] + ra[2][t] + ra[3][t];
        float m = rm[0] + rm[1] + rm[2] + rm[3];
        feats[b * 4096 + blockIdx.z * 1024 + d0 + t] = a / fmaxf(m, 1e-9f);
    }
}

__global__ __launch_bounds__(256) void pool_bf16_kernel(const __bf16* __restrict__ X,
                                                        const float* __restrict__ mask,
                                                        int half, float* __restrict__ feats,
                                                        int off)
{
    const int b = blockIdx.y, d0 = blockIdx.x * 64;
    const int t = threadIdx.x, d = d0 + (t & 63), sl = t >> 6;
    float acc = 0.f, ms = 0.f;
#pragma unroll 4
    for (int s = sl * 128; s < sl * 128 + 128; ++s) {
        float m = mask[b * 1024 + half + s];
        acc += (float)X[((size_t)b * 512 + s) * 1024 + d] * m;
        ms += m;
    }
    __shared__ float ra[4][64];
    __shared__ float rm[4];
    ra[sl][t & 63] = acc;
    if ((t & 63) == 0) rm[sl] = ms;
    __syncthreads();
    if (t < 64) {
        float a = ra[0][t] + ra[1][t] + ra[2][t] + ra[3][t];
        float m = rm[0] + rm[1] + rm[2] + rm[3];
        feats[b * 4096 + off + d0 + t] = a / fmaxf(m, 1e-9f);
    }
}

// ---------------------------------------------------------------- small fp32 MLP
__global__ __launch_bounds__(256) void fc_init_kernel(const float* __restrict__ b1,
                                                      const float* __restrict__ b2,
                                                      float* __restrict__ h1,
                                                      float* __restrict__ h2)
{
    int i = blockIdx.x * 256 + threadIdx.x;
    if (i < 16 * 1024) h1[i] = b1[i & 1023];
    else h2[i - 16 * 1024] = b2[(i - 16 * 1024) & 511];
}

template <int CH, int RELU_IN>
__global__ __launch_bounds__(256) void fc_atomic_kernel(const float* __restrict__ in,
                                                        const float* __restrict__ W,
                                                        float* __restrict__ out,
                                                        int IF, int OF)
{
    __shared__ float ins[16 * CH];
    const int t = threadIdx.x;
    const int col = blockIdx.x * 256 + t;
    const int i0 = blockIdx.y * CH;
#pragma unroll
    for (int idx = t; idx < 16 * CH; idx += 256) {
        int b = idx / CH, i = idx % CH;
        float v = in[b * IF + i0 + i];
        if (RELU_IN) v = fmaxf(v, 0.f);
        ins[idx] = v;
    }
    __syncthreads();
    float acc[16];
#pragma unroll
    for (int b = 0; b < 16; ++b) acc[b] = 0.f;
#pragma unroll 4
    for (int i = 0; i < CH; ++i) {
        float wv = W[(size_t)(i0 + i) * OF + col];
#pragma unroll
        for (int b = 0; b < 16; ++b) acc[b] += ins[b * CH + i] * wv;
    }
#pragma unroll
    for (int b = 0; b < 16; ++b) atomicAdd(out + b * OF + col, acc[b]);
}

__global__ __launch_bounds__(64) void mlp3_kernel(const float* __restrict__ h2,
                                                  const float* __restrict__ W3,
                                                  const float* __restrict__ b3,
                                                  float* __restrict__ out)
{
    int b = blockIdx.x, t = threadIdx.x;
    float a0 = 0.f, a1 = 0.f, a2 = 0.f;
    for (int i = t; i < 512; i += 64) {
        float hv = fmaxf(h2[b * 512 + i], 0.f);
        a0 += hv * W3[i * 3 + 0];
        a1 += hv * W3[i * 3 + 1];
        a2 += hv * W3[i * 3 + 2];
    }
#pragma unroll
    for (int d = 1; d < 64; d <<= 1) {
        a0 += __shfl_xor(a0, d);
        a1 += __shfl_xor(a1, d);
        a2 += __shfl_xor(a2, d);
    }
    if (t == 0) {
        out[b * 3 + 0] = a0 + b3[0];
        out[b * 3 + 1] = a1 + b3[1];
        out[b * 3 + 2] = a2 + b3[2];
    }
}

// ---------------------------------------------------------------- launch
extern "C" void kernel_launch(void* const* d_in, const int* in_sizes, int n_in,
                              void* d_out, int out_size, void* d_ws, size_t ws_size,
                              hipStream_t stream)
{
    const float* emb  = (const float*)d_in[0];
    const float* mask = (const float*)d_in[1];
    const float* W1 = (const float*)d_in[22];
    const float* b1 = (const float*)d_in[23];
    const float* W2 = (const float*)d_in[24];
    const float* b2 = (const float*)d_in[25];
    const float* W3 = (const float*)d_in[26];
    const float* b3 = (const float*)d_in[27];

    char* ws = (char*)d_ws;
    constexpr size_t MB = 1ull << 20;
    __bf16* Pb    = (__bf16*)(ws);                 // 16 MB (8192,1024) bf16
    __bf16* Hb    = (__bf16*)(ws + 16 * MB);       // 16 MB
    __bf16* Wt    = (__bf16*)(ws + 32 * MB);       // 16 MB: 8 x (1024,1024) bf16 W^T
    __bf16* Qb    = (__bf16*)(ws + 48 * MB);       // 16 MB
    __bf16* Kb    = (__bf16*)(ws + 64 * MB);       // 16 MB
    __bf16* Vt    = (__bf16*)(ws + 80 * MB);       // 16 MB (B,H,64,512)
    __bf16* attb  = (__bf16*)(ws + 96 * MB);       // 16 MB
    float*  Of    = (float*) (ws + 48 * MB);       // 32 MB, aliases Qb+Kb (dead by then)
    __bf16* ctx   = (__bf16*)(ws + 112 * MB);      // 16 MB
    float*  feats = (float*) (ws + 128 * MB);      // 256 KB (16,4096)
    float*  h1    = (float*) (ws + 128 * MB + 512 * 1024);  // 64 KB
    float*  h2    = (float*) (ws + 129 * MB);      // 32 KB

    cast_emb_kernel<<<8192, 256, 0, stream>>>(emb, Pb, Hb);
    WPtrs wp;
    const int widx[8] = {2, 4, 6, 8, 12, 14, 16, 18};   // p2h Wq,Wk,Wv,Wo then h2p
    for (int i = 0; i < 8; ++i) wp.p[i] = (const float*)d_in[widx[i]];
    cast_wt_kernel<<<dim3(32, 32, 8), dim3(32, 8), 0, stream>>>(wp, Wt);

    dim3 gg(8, 64);     // (N/128, M/128) for N=1024
    dim3 gkv(16, 64);   // N=2048 fused K|V
    for (int dir = 0; dir < 2; ++dir) {
        const __bf16* qin  = dir ? Hb : Pb;
        const __bf16* kvin = dir ? Pb : Hb;
        const int base = dir ? 12 : 2;
        const __bf16* wq  = Wt + (size_t)(dir * 4 + 0) * 1048576;
        const __bf16* wkv = Wt + (size_t)(dir * 4 + 1) * 1048576;  // Wk|Wv contiguous
        const __bf16* wo  = Wt + (size_t)(dir * 4 + 3) * 1048576;
        const float* bq  = (const float*)d_in[base + 1];
        const float* bk  = (const float*)d_in[base + 3];
        const float* bv  = (const float*)d_in[base + 5];
        const float* bo  = (const float*)d_in[base + 7];
        const float* lng = (const float*)d_in[base + 8];
        const float* lnb = (const float*)d_in[base + 9];
        const int kvhalf  = dir ? 0 : 512;    // p2h attends hypothesis (mask half 512)
        const int reshalf = dir ? 512 : 0;    // residual = q_in slice of embedded

        gemm_bt<0><<<gg, 256, 0, stream>>>(qin, wq, bq, nullptr, Qb, nullptr,
                                           nullptr, nullptr, 0, 8192, 1024, 1024);
        gemm_bt<3><<<gkv, 256, 0, stream>>>(kvin, wkv, bk, bv, Kb, Vt,
                                            nullptr, nullptr, 0, 8192, 2048, 1024);
        attn_kernel<<<dim3(256, 8), 256, 0, stream>>>(Qb, Kb, Vt, mask, kvhalf, attb);
        gemm_bt<2><<<gg, 256, 0, stream>>>(attb, wo, bo, nullptr, nullptr, nullptr,
                                           Of, emb, reshalf, 8192, 1024, 1024);
        ln_kernel<<<8192, 256, 0, stream>>>(Of, lng, lnb, ctx);
        pool_bf16_kernel<<<dim3(16, 16), 256, 0, stream>>>(ctx, mask, dir ? 512 : 0,
                                                           feats, 2048 + dir * 1024);
    }
    pool_f32_kernel<<<dim3(16, 16, 2), 256, 0, stream>>>(emb, mask, feats);

    fc_init_kernel<<<96, 256, 0, stream>>>(b1, b2, h1, h2);
    fc_atomic_kernel<128, 0><<<dim3(4, 32), 256, 0, stream>>>(feats, W1, h1, 4096, 1024);
    fc_atomic_kernel<32, 1><<<dim3(2, 32), 256, 0, stream>>>(h1, W2, h2, 1024, 512);
    mlp3_kernel<<<16, 64, 0, stream>>>(h2, W3, b3, (float*)d_out);
}

// Round 9
// 603.387 us; speedup vs baseline: 1.1109x; 1.0030x over previous
//
#include <hip/hip_runtime.h>
#include <hip/hip_bf16.h>

typedef __attribute__((ext_vector_type(8))) __bf16 bf16x8;
typedef __attribute__((ext_vector_type(4))) float f32x4;
typedef __attribute__((ext_vector_type(4))) int i32x4;
typedef __attribute__((ext_vector_type(4))) unsigned short u16x4;

#define MFMA16(a, b, c) __builtin_amdgcn_mfma_f32_16x16x32_bf16((a), (b), (c), 0, 0, 0)

__device__ __forceinline__ void gload_lds16(const void* g, void* l)
{
    __builtin_amdgcn_global_load_lds(
        (const __attribute__((address_space(1))) unsigned int*)g,
        (__attribute__((address_space(3))) unsigned int*)l, 16, 0, 0);
}

// ---------------------------------------------------------------- casts
__global__ __launch_bounds__(256) void cast_emb_kernel(const float* __restrict__ emb,
                                                       __bf16* __restrict__ Pb,
                                                       __bf16* __restrict__ Hb)
{
    int i = (blockIdx.x * 256 + threadIdx.x) * 4;
    int r = i >> 10, d = i & 1023;
    size_t src = ((size_t)(r >> 9) * 1024 + (r & 511)) * 1024 + d;
    f32x4 p = *(const f32x4*)(emb + src);
    f32x4 h = *(const f32x4*)(emb + src + 512 * 1024);
    union { __bf16 b[4]; u16x4 u; } cp, ch;
#pragma unroll
    for (int j = 0; j < 4; ++j) { cp.b[j] = (__bf16)p[j]; ch.b[j] = (__bf16)h[j]; }
    *(u16x4*)(Pb + i) = cp.u;
    *(u16x4*)(Hb + i) = ch.u;
}

struct WPtrs { const float* p[8]; };
__global__ __launch_bounds__(256) void cast_wt_kernel(WPtrs wp, __bf16* __restrict__ Wt0)
{
    const float* W = wp.p[blockIdx.z];
    __bf16* Wt = Wt0 + (size_t)blockIdx.z * 1048576;
    __shared__ float tile[32][33];
    int n0 = blockIdx.x * 32, k0 = blockIdx.y * 32;
    int tx = threadIdx.x, ty = threadIdx.y;
#pragma unroll
    for (int i = ty; i < 32; i += 8)
        tile[i][tx] = W[(size_t)(k0 + i) * 1024 + n0 + tx];
    __syncthreads();
#pragma unroll
    for (int i = ty; i < 32; i += 8)
        Wt[(size_t)(n0 + i) * 1024 + k0 + tx] = (__bf16)tile[tx][i];
}

// ---------------------------------------------------------------- GEMM (m97 structure)
// EPI 0: Cb = bf16(v)   EPI 2: Cf = v + resid (fp32)
// EPI 3: N=2048 K|V: col<1024 -> Cb (K); col>=1024 -> Cb2 V-transpose (B,H,64,512)
// (256,2): VGPR cap 256 — m97 GEMM needs ~164V+64A=228; (256,3)'s 170 cap
// register-starved it (R6-R8 regression).
template <int EPI>
__global__ __launch_bounds__(256, 2) void gemm_bt(const __bf16* __restrict__ A,
                                                  const __bf16* __restrict__ Bt,
                                                  const float* __restrict__ bias,
                                                  const float* __restrict__ bias2,
                                                  __bf16* __restrict__ Cb,
                                                  __bf16* __restrict__ Cb2,
                                                  float* __restrict__ Cf,
                                                  const float* __restrict__ resid,
                                                  int resid_half, int M, int N, int K)
{
    __shared__ __align__(16) __bf16 As[128 * 32];
    __shared__ __align__(16) __bf16 Bs[128 * 32];
    const int t = threadIdx.x;
    const int l = t & 63, w = t >> 6;
    const int wr = w >> 1, wc = w & 1;
    const int lrow = l & 15, lk = l >> 4;
    const int m0 = blockIdx.y * 128, n0 = blockIdx.x * 128;
    const int r0 = t >> 2, kc0 = (t & 3) * 8;

    const __bf16* gA0 = A + (size_t)(m0 + r0) * K + kc0;
    const __bf16* gA1 = gA0 + (size_t)64 * K;
    const __bf16* gB0 = Bt + (size_t)(n0 + r0) * K + kc0;
    const __bf16* gB1 = gB0 + (size_t)64 * K;
    __bf16* dA0 = &As[r0 * 32 + kc0];
    __bf16* dA1 = &As[(r0 + 64) * 32 + kc0];
    __bf16* dB0 = &Bs[r0 * 32 + kc0];
    __bf16* dB1 = &Bs[(r0 + 64) * 32 + kc0];

    const f32x4 zero = {0.f, 0.f, 0.f, 0.f};
    f32x4 acc[4][4];
#pragma unroll
    for (int mi = 0; mi < 4; ++mi)
#pragma unroll
        for (int ni = 0; ni < 4; ++ni) acc[mi][ni] = zero;

    const int nk = K >> 5;
    for (int kt = 0; kt < nk; ++kt) {
        const int ko = kt * 32;
        gload_lds16(gA0 + ko, dA0);
        gload_lds16(gA1 + ko, dA1);
        gload_lds16(gB0 + ko, dB0);
        gload_lds16(gB1 + ko, dB1);
        __syncthreads();
        bf16x8 af[4], bfv[4];
#pragma unroll
        for (int mi = 0; mi < 4; ++mi)
            af[mi] = *(const bf16x8*)(&As[(wr * 64 + mi * 16 + lrow) * 32 + lk * 8]);
#pragma unroll
        for (int ni = 0; ni < 4; ++ni)
            bfv[ni] = *(const bf16x8*)(&Bs[(wc * 64 + ni * 16 + lrow) * 32 + lk * 8]);
#pragma unroll
        for (int mi = 0; mi < 4; ++mi)
#pragma unroll
            for (int ni = 0; ni < 4; ++ni)
                acc[mi][ni] = MFMA16(af[mi], bfv[ni], acc[mi][ni]);
        __syncthreads();
    }

#pragma unroll
    for (int mi = 0; mi < 4; ++mi) {
#pragma unroll
        for (int ni = 0; ni < 4; ++ni) {
            int col = n0 + wc * 64 + ni * 16 + lrow;
            float bv = (EPI == 3 && col >= 1024) ? bias2[col - 1024] : bias[col];
#pragma unroll
            for (int r = 0; r < 4; ++r) {
                int row = m0 + wr * 64 + mi * 16 + lk * 4 + r;
                float v = acc[mi][ni][r] + bv;
                if (EPI == 0) {
                    Cb[(size_t)row * N + col] = (__bf16)v;
                } else if (EPI == 3) {
                    if (col < 1024) {
                        Cb[(size_t)row * 1024 + col] = (__bf16)v;
                    } else {
                        int c2 = col - 1024;
                        int b_ = row >> 9, pos = row & 511;
                        int h_ = c2 >> 6, hd = c2 & 63;
                        Cb2[(((size_t)(b_ * 16 + h_) * 64 + hd) << 9) + pos] = (__bf16)v;
                    }
                } else {
                    int b_ = row >> 9, s = row & 511;
                    float rv = resid[((size_t)b_ * 1024 + resid_half + s) * 1024 + col];
                    Cf[(size_t)row * N + col] = v + rv;
                }
            }
        }
    }
}

// ---------------------------------------------------------------- attention
// Pipelined flash attention: 4 K-tiles of 128 pos, K double-buffered (2x16KB),
// P in its own 16KB buffer (wave-private rows -> no P barriers). One barrier
// per tile; stage(t+1) is issued AFTER qk(t) and drains at tile t+1's
// __syncthreads -> its latency hides under softmax+PV of tile t.
// Hazard: stage(t+1) overwrites buf[(t+1)&1], last read by qk(t-1); all waves
// passed tile t's barrier after qk(t-1) -> plain __syncthreads suffices.
// Swapped QK^T (mfma(K,Q)): lane owns softmax row q = w*16+lrow.
__global__ __launch_bounds__(256, 3) void attn_kernel(const __bf16* __restrict__ Q,
                                                      const __bf16* __restrict__ Kb,
                                                      const __bf16* __restrict__ Vt,
                                                      const float* __restrict__ mask,
                                                      int mask_half,
                                                      __bf16* __restrict__ att)
{
    __shared__ __align__(16) __bf16 KB[2][128 * 64];  // 2 x 16 KB K tiles (swizzled)
    __shared__ __align__(16) __bf16 Pt[64 * 128];     // 16 KB P tile
    __shared__ __align__(16) float msk[512];
    const int bh = blockIdx.x, b = bh >> 4, h = bh & 15;
    const int q0 = blockIdx.y * 64;
    const int tid = threadIdx.x, l = tid & 63, w = tid >> 6;
    const int lrow = l & 15, lk = l >> 4;

    const __bf16* kbase = Kb + ((size_t)b * 512) * 1024 + h * 64;
    const __bf16* vsrc = Vt + (size_t)bh * 64 * 512;

    auto stage = [&](int t, int buf) {
        char* dst = (char*)KB[buf];
#pragma unroll
        for (int i = 0; i < 4; ++i) {
            int c = tid + i * 256;
            int pos = c >> 3, gslot = (c & 7) ^ (pos & 7);
            gload_lds16(kbase + (size_t)(t * 128 + pos) * 1024 + gslot * 8, dst + c * 16);
        }
    };

    stage(0, 0);
    for (int i = tid; i < 512; i += 256) msk[i] = mask[b * 1024 + mask_half + i];

    const int qrow = q0 + w * 16 + lrow;
    const __bf16* qptr = Q + ((size_t)(b * 512 + qrow)) * 1024 + h * 64;
    bf16x8 qf0 = *(const bf16x8*)(qptr + lk * 8);
    bf16x8 qf1 = *(const bf16x8*)(qptr + 32 + lk * 8);

    const f32x4 zero = {0.f, 0.f, 0.f, 0.f};
    f32x4 av[4];
#pragma unroll
    for (int ni = 0; ni < 4; ++ni) av[ni] = zero;
    float m_run = -3e38f, su = 0.f;
    const int psw = lrow & 7;
    char* prowp = (char*)Pt + (w * 16 + lrow) * 256;   // P row = 128 k x 2B = 16 slots
    f32x4 sc[8];

#pragma unroll
    for (int t = 0; t < 4; ++t) {
        __syncthreads();   // K[t] staged (own vmcnt drained) + all waves past qk(t-1)
        const char* kbuf = (const char*)KB[t & 1];
#pragma unroll
        for (int jj = 0; jj < 8; ++jj) {
            const char* kb = kbuf + (jj * 16 + lrow) * 128;
            bf16x8 k0 = *(const bf16x8*)(kb + ((lk ^ psw) << 4));
            bf16x8 k1 = *(const bf16x8*)(kb + (((lk + 4) ^ psw) << 4));
            f32x4 c = zero;
            c = MFMA16(k0, qf0, c);    // swapped: C[row=k local][col=q local]
            c = MFMA16(k1, qf1, c);
            sc[jj] = c;
        }
        if (t < 3) stage(t + 1, (t + 1) & 1);   // prefetch; hides under softmax+PV

        // ---- online softmax over this 128-tile
        const int koff = t * 128;
        float mt = -3e38f;
#pragma unroll
        for (int jj = 0; jj < 8; ++jj) {
            f32x4 mv = *(const f32x4*)(&msk[koff + jj * 16 + lk * 4]);
#pragma unroll
            for (int r = 0; r < 4; ++r) {
                float s = sc[jj][r] * 0.125f;   // 1/sqrt(64)
                if (mv[r] == 0.f) s = -1e9f;
                sc[jj][r] = s;
                mt = fmaxf(mt, s);
            }
        }
        mt = fmaxf(mt, __shfl_xor(mt, 16));
        mt = fmaxf(mt, __shfl_xor(mt, 32));
        float m_new = fmaxf(m_run, mt);
        float f = __expf(m_run - m_new);
        float s0 = 0.f, s1 = 0.f;   // 2 partials for ILP on the add chain
#pragma unroll
        for (int jj = 0; jj < 8; ++jj) {
            float e0 = __expf(sc[jj][0] - m_new);
            float e1 = __expf(sc[jj][1] - m_new);
            float e2 = __expf(sc[jj][2] - m_new);
            float e3 = __expf(sc[jj][3] - m_new);
            sc[jj][0] = e0; sc[jj][1] = e1; sc[jj][2] = e2; sc[jj][3] = e3;
            s0 += e0 + e1;
            s1 += e2 + e3;
        }
        float ssum = s0 + s1;
        ssum += __shfl_xor(ssum, 16);
        ssum += __shfl_xor(ssum, 32);
        su = su * f + ssum;
        m_run = m_new;
#pragma unroll
        for (int r = 0; r < 4; ++r) {
            float fr = __shfl(f, (l & 48) | (lk * 4 + r));
#pragma unroll
            for (int ni = 0; ni < 4; ++ni) av[ni][r] *= fr;
        }

        // ---- P write (wave-private rows, packed b64, swizzled 16B slots)
#pragma unroll
        for (int jj = 0; jj < 8; ++jj) {
            union { __bf16 b[4]; unsigned long long u; } pk;
#pragma unroll
            for (int r = 0; r < 4; ++r) pk.b[r] = (__bf16)sc[jj][r];
            int slot2 = jj * 2 + (lk >> 1);
            *(unsigned long long*)(prowp + (((slot2 ^ psw) << 4) | ((lk & 1) << 3))) = pk.u;
        }
        // ---- PV
#pragma unroll
        for (int ks = 0; ks < 4; ++ks) {
            bf16x8 pf = *(const bf16x8*)(prowp + (((ks * 4 + lk) ^ psw) << 4));
#pragma unroll
            for (int ni = 0; ni < 4; ++ni) {
                bf16x8 vf = *(const bf16x8*)(&vsrc[(ni * 16 + lrow) * 512 + koff + ks * 32 + lk * 8]);
                av[ni] = MFMA16(pf, vf, av[ni]);
            }
        }
    }

    const float inv = 1.f / su;
#pragma unroll
    for (int r = 0; r < 4; ++r) {
        float ivr = __shfl(inv, (l & 48) | (lk * 4 + r));
        int qq = q0 + w * 16 + lk * 4 + r;
#pragma unroll
        for (int ni = 0; ni < 4; ++ni)
            att[((size_t)(b * 512 + qq)) * 1024 + h * 64 + ni * 16 + lrow] =
                (__bf16)(av[ni][r] * ivr);
    }
}

// ---------------------------------------------------------------- layernorm (row of 1024)
__global__ __launch_bounds__(256) void ln_kernel(const float* __restrict__ X,
                                                 const float* __restrict__ g,
                                                 const float* __restrict__ bta,
                                                 __bf16* __restrict__ out)
{
    const int r = blockIdx.x, t = threadIdx.x;
    const float* x = X + (size_t)r * 1024;
    f32x4 v = *(const f32x4*)(x + t * 4);
    float s = v[0] + v[1] + v[2] + v[3];
    float q = v[0] * v[0] + v[1] * v[1] + v[2] * v[2] + v[3] * v[3];
#pragma unroll
    for (int d = 1; d < 64; d <<= 1) { s += __shfl_xor(s, d); q += __shfl_xor(q, d); }
    __shared__ float rs[4], rq[4];
    if ((t & 63) == 0) { rs[t >> 6] = s; rq[t >> 6] = q; }
    __syncthreads();
    s = rs[0] + rs[1] + rs[2] + rs[3];
    q = rq[0] + rq[1] + rq[2] + rq[3];
    float mu = s * (1.f / 1024.f);
    float var = q * (1.f / 1024.f) - mu * mu;
    float rstd = rsqrtf(var + 1e-5f);
#pragma unroll
    for (int j = 0; j < 4; ++j) {
        int c = t * 4 + j;
        out[(size_t)r * 1024 + c] = (__bf16)((v[j] - mu) * rstd * g[c] + bta[c]);
    }
}

// ---------------------------------------------------------------- pools
__global__ __launch_bounds__(256) void pool_f32_kernel(const float* __restrict__ X,
                                                       const float* __restrict__ mask,
                                                       float* __restrict__ feats)
{
    const int b = blockIdx.y, d0 = blockIdx.x * 64, half = blockIdx.z * 512;
    const int t = threadIdx.x, d = d0 + (t & 63), sl = t >> 6;
    float acc = 0.f, ms = 0.f;
#pragma unroll 4
    for (int s = sl * 128; s < sl * 128 + 128; ++s) {
        float m = mask[b * 1024 + half + s];
        acc += X[((size_t)b * 1024 + half + s) * 1024 + d] * m;
        ms += m;
    }
    __shared__ float ra[4][64];
    __shared__ float rm[4];
    ra[sl][t & 63] = acc;
    if ((t & 63) == 0) rm[sl] = ms;
    __syncthreads();
    if (t < 64) {
        float a = ra[0][t] + ra[1][t] + ra[2][t] + ra[3][t];
        float m = rm[0] + rm[1] + rm[2] + rm[3];
        feats[b * 4096 + blockIdx.z * 1024 + d0 + t] = a / fmaxf(m, 1e-9f);
    }
}

__global__ __launch_bounds__(256) void pool_bf16_kernel(const __bf16* __restrict__ X,
                                                        const float* __restrict__ mask,
                                                        int half, float* __restrict__ feats,
                                                        int off)
{
    const int b = blockIdx.y, d0 = blockIdx.x * 64;
    const int t = threadIdx.x, d = d0 + (t & 63), sl = t >> 6;
    float acc = 0.f, ms = 0.f;
#pragma unroll 4
    for (int s = sl * 128; s < sl * 128 + 128; ++s) {
        float m = mask[b * 1024 + half + s];
        acc += (float)X[((size_t)b * 512 + s) * 1024 + d] * m;
        ms += m;
    }
    __shared__ float ra[4][64];
    __shared__ float rm[4];
    ra[sl][t & 63] = acc;
    if ((t & 63) == 0) rm[sl] = ms;
    __syncthreads();
    if (t < 64) {
        float a = ra[0][t] + ra[1][t] + ra[2][t] + ra[3][t];
        float m = rm[0] + rm[1] + rm[2] + rm[3];
        feats[b * 4096 + off + d0 + t] = a / fmaxf(m, 1e-9f);
    }
}

// ---------------------------------------------------------------- small fp32 MLP
__global__ __launch_bounds__(256) void fc_init_kernel(const float* __restrict__ b1,
                                                      const float* __restrict__ b2,
                                                      float* __restrict__ h1,
                                                      float* __restrict__ h2)
{
    int i = blockIdx.x * 256 + threadIdx.x;
    if (i < 16 * 1024) h1[i] = b1[i & 1023];
    else h2[i - 16 * 1024] = b2[(i - 16 * 1024) & 511];
}

template <int CH, int RELU_IN>
__global__ __launch_bounds__(256) void fc_atomic_kernel(const float* __restrict__ in,
                                                        const float* __restrict__ W,
                                                        float* __restrict__ out,
                                                        int IF, int OF)
{
    __shared__ float ins[16 * CH];
    const int t = threadIdx.x;
    const int col = blockIdx.x * 256 + t;
    const int i0 = blockIdx.y * CH;
#pragma unroll
    for (int idx = t; idx < 16 * CH; idx += 256) {
        int b = idx / CH, i = idx % CH;
        float v = in[b * IF + i0 + i];
        if (RELU_IN) v = fmaxf(v, 0.f);
        ins[idx] = v;
    }
    __syncthreads();
    float acc[16];
#pragma unroll
    for (int b = 0; b < 16; ++b) acc[b] = 0.f;
#pragma unroll 4
    for (int i = 0; i < CH; ++i) {
        float wv = W[(size_t)(i0 + i) * OF + col];
#pragma unroll
        for (int b = 0; b < 16; ++b) acc[b] += ins[b * CH + i] * wv;
    }
#pragma unroll
    for (int b = 0; b < 16; ++b) atomicAdd(out + b * OF + col, acc[b]);
}

__global__ __launch_bounds__(64) void mlp3_kernel(const float* __restrict__ h2,
                                                  const float* __restrict__ W3,
                                                  const float* __restrict__ b3,
                                                  float* __restrict__ out)
{
    int b = blockIdx.x, t = threadIdx.x;
    float a0 = 0.f, a1 = 0.f, a2 = 0.f;
    for (int i = t; i < 512; i += 64) {
        float hv = fmaxf(h2[b * 512 + i], 0.f);
        a0 += hv * W3[i * 3 + 0];
        a1 += hv * W3[i * 3 + 1];
        a2 += hv * W3[i * 3 + 2];
    }
#pragma unroll
    for (int d = 1; d < 64; d <<= 1) {
        a0 += __shfl_xor(a0, d);
        a1 += __shfl_xor(a1, d);
        a2 += __shfl_xor(a2, d);
    }
    if (t == 0) {
        out[b * 3 + 0] = a0 + b3[0];
        out[b * 3 + 1] = a1 + b3[1];
        out[b * 3 + 2] = a2 + b3[2];
    }
}

// ---------------------------------------------------------------- launch
extern "C" void kernel_launch(void* const* d_in, const int* in_sizes, int n_in,
                              void* d_out, int out_size, void* d_ws, size_t ws_size,
                              hipStream_t stream)
{
    const float* emb  = (const float*)d_in[0];
    const float* mask = (const float*)d_in[1];
    const float* W1 = (const float*)d_in[22];
    const float* b1 = (const float*)d_in[23];
    const float* W2 = (const float*)d_in[24];
    const float* b2 = (const float*)d_in[25];
    const float* W3 = (const float*)d_in[26];
    const float* b3 = (const float*)d_in[27];

    char* ws = (char*)d_ws;
    constexpr size_t MB = 1ull << 20;
    __bf16* Pb    = (__bf16*)(ws);                 // 16 MB (8192,1024) bf16
    __bf16* Hb    = (__bf16*)(ws + 16 * MB);       // 16 MB
    __bf16* Wt    = (__bf16*)(ws + 32 * MB);       // 16 MB: 8 x (1024,1024) bf16 W^T
    __bf16* Qb    = (__bf16*)(ws + 48 * MB);       // 16 MB
    __bf16* Kb    = (__bf16*)(ws + 64 * MB);       // 16 MB
    __bf16* Vt    = (__bf16*)(ws + 80 * MB);       // 16 MB (B,H,64,512)
    __bf16* attb  = (__bf16*)(ws + 96 * MB);       // 16 MB
    float*  Of    = (float*) (ws + 48 * MB);       // 32 MB, aliases Qb+Kb (dead by then)
    __bf16* ctx   = (__bf16*)(ws + 112 * MB);      // 16 MB
    float*  feats = (float*) (ws + 128 * MB);      // 256 KB (16,4096)
    float*  h1    = (float*) (ws + 128 * MB + 512 * 1024);  // 64 KB
    float*  h2    = (float*) (ws + 129 * MB);      // 32 KB

    cast_emb_kernel<<<8192, 256, 0, stream>>>(emb, Pb, Hb);
    WPtrs wp;
    const int widx[8] = {2, 4, 6, 8, 12, 14, 16, 18};   // p2h Wq,Wk,Wv,Wo then h2p
    for (int i = 0; i < 8; ++i) wp.p[i] = (const float*)d_in[widx[i]];
    cast_wt_kernel<<<dim3(32, 32, 8), dim3(32, 8), 0, stream>>>(wp, Wt);

    dim3 gg(8, 64);     // (N/128, M/128) for N=1024
    dim3 gkv(16, 64);   // N=2048 fused K|V
    for (int dir = 0; dir < 2; ++dir) {
        const __bf16* qin  = dir ? Hb : Pb;
        const __bf16* kvin = dir ? Pb : Hb;
        const int base = dir ? 12 : 2;
        const __bf16* wq  = Wt + (size_t)(dir * 4 + 0) * 1048576;
        const __bf16* wkv = Wt + (size_t)(dir * 4 + 1) * 1048576;  // Wk|Wv contiguous
        const __bf16* wo  = Wt + (size_t)(dir * 4 + 3) * 1048576;
        const float* bq  = (const float*)d_in[base + 1];
        const float* bk  = (const float*)d_in[base + 3];
        const float* bv  = (const float*)d_in[base + 5];
        const float* bo  = (const float*)d_in[base + 7];
        const float* lng = (const float*)d_in[base + 8];
        const float* lnb = (const float*)d_in[base + 9];
        const int kvhalf  = dir ? 0 : 512;    // p2h attends hypothesis (mask half 512)
        const int reshalf = dir ? 512 : 0;    // residual = q_in slice of embedded

        gemm_bt<0><<<gg, 256, 0, stream>>>(qin, wq, bq, nullptr, Qb, nullptr,
                                           nullptr, nullptr, 0, 8192, 1024, 1024);
        gemm_bt<3><<<gkv, 256, 0, stream>>>(kvin, wkv, bk, bv, Kb, Vt,
                                            nullptr, nullptr, 0, 8192, 2048, 1024);
        attn_kernel<<<dim3(256, 8), 256, 0, stream>>>(Qb, Kb, Vt, mask, kvhalf, attb);
        gemm_bt<2><<<gg, 256, 0, stream>>>(attb, wo, bo, nullptr, nullptr, nullptr,
                                           Of, emb, reshalf, 8192, 1024, 1024);
        ln_kernel<<<8192, 256, 0, stream>>>(Of, lng, lnb, ctx);
        pool_bf16_kernel<<<dim3(16, 16), 256, 0, stream>>>(ctx, mask, dir ? 512 : 0,
                                                           feats, 2048 + dir * 1024);
    }
    pool_f32_kernel<<<dim3(16, 16, 2), 256, 0, stream>>>(emb, mask, feats);

    fc_init_kernel<<<96, 256, 0, stream>>>(b1, b2, h1, h2);
    fc_atomic_kernel<128, 0><<<dim3(4, 32), 256, 0, stream>>>(feats, W1, h1, 4096, 1024);
    fc_atomic_kernel<32, 1><<<dim3(2, 32), 256, 0, stream>>>(h1, W2, h2, 1024, 512);
    mlp3_kernel<<<16, 64, 0, stream>>>(h2, W3, b3, (float*)d_out);
}

// Round 10
// 569.202 us; speedup vs baseline: 1.1776x; 1.0601x over previous
//
#include <hip/hip_runtime.h>
#include <hip/hip_bf16.h>

typedef __attribute__((ext_vector_type(8))) __bf16 bf16x8;
typedef __attribute__((ext_vector_type(4))) float f32x4;
typedef __attribute__((ext_vector_type(4))) int i32x4;
typedef __attribute__((ext_vector_type(4))) unsigned short u16x4;

#define MFMA16(a, b, c) __builtin_amdgcn_mfma_f32_16x16x32_bf16((a), (b), (c), 0, 0, 0)

__device__ __forceinline__ void gload_lds16(const void* g, void* l)
{
    __builtin_amdgcn_global_load_lds(
        (const __attribute__((address_space(1))) unsigned int*)g,
        (__attribute__((address_space(3))) unsigned int*)l, 16, 0, 0);
}

struct GemmW { const __bf16* w[2]; const float* bias[2]; const float* bias2[2]; };
struct LnW   { const float* g[2]; const float* b[2]; };

// ---------------------------------------------------------------- casts
// embedded (B,1024,1024) fp32 -> A = [premise rows 0..8191 | hypothesis 8192..16383] bf16
__global__ __launch_bounds__(256) void cast_emb_kernel(const float* __restrict__ emb,
                                                       __bf16* __restrict__ A)
{
    int i = (blockIdx.x * 256 + threadIdx.x) * 4;   // element in (8192,1024) premise space
    int r = i >> 10, d = i & 1023;
    size_t src = ((size_t)(r >> 9) * 1024 + (r & 511)) * 1024 + d;
    f32x4 p = *(const f32x4*)(emb + src);
    f32x4 h = *(const f32x4*)(emb + src + 512 * 1024);
    union { __bf16 b[4]; u16x4 u; } cp, ch;
#pragma unroll
    for (int j = 0; j < 4; ++j) { cp.b[j] = (__bf16)p[j]; ch.b[j] = (__bf16)h[j]; }
    *(u16x4*)(A + i) = cp.u;
    *(u16x4*)(A + 8388608 + i) = ch.u;
}

// 8 weights W (1024,1024) fp32 row-major -> Wt bf16, Wt[n][k] = W[k][n]
struct WPtrs { const float* p[8]; };
__global__ __launch_bounds__(256) void cast_wt_kernel(WPtrs wp, __bf16* __restrict__ Wt0)
{
    const float* W = wp.p[blockIdx.z];
    __bf16* Wt = Wt0 + (size_t)blockIdx.z * 1048576;
    __shared__ float tile[32][33];
    int n0 = blockIdx.x * 32, k0 = blockIdx.y * 32;
    int tx = threadIdx.x, ty = threadIdx.y;
#pragma unroll
    for (int i = ty; i < 32; i += 8)
        tile[i][tx] = W[(size_t)(k0 + i) * 1024 + n0 + tx];
    __syncthreads();
#pragma unroll
    for (int i = ty; i < 32; i += 8)
        Wt[(size_t)(n0 + i) * 1024 + k0 + tx] = (__bf16)tile[tx][i];
}

// ---------------------------------------------------------------- GEMM (m97 structure)
// Merged 2-direction GEMM: M=16384, dir = m0>>13 selects weights/biases.
// EPI 0 (Q):  C row = A row (direct).  Cb[row*1024+col] = bf16.
// EPI 3 (KV): A row = C row ^ 8192 (dir0 KV comes from hypothesis rows & v.v.)
//             col<1024 -> Kb[row*1024+col]; col>=1024 -> Vt dir seg, (B,H,64,512).
// EPI 2 (O):  direct rows; Cf = v + resid (emb slice per dir).
// (256,3): empirically best (R4 vs R9 A/B: non-attn 404 vs 427 us).
template <int EPI>
__global__ __launch_bounds__(256, 3) void gemm_bt(const __bf16* __restrict__ A,
                                                  GemmW gw,
                                                  __bf16* __restrict__ Cb,
                                                  __bf16* __restrict__ Vt,
                                                  float* __restrict__ Cf,
                                                  const float* __restrict__ resid,
                                                  int K)
{
    __shared__ __align__(16) __bf16 As[128 * 32];
    __shared__ __align__(16) __bf16 Bs[128 * 32];
    const int t = threadIdx.x;
    const int l = t & 63, w = t >> 6;
    const int wr = w >> 1, wc = w & 1;
    const int lrow = l & 15, lk = l >> 4;
    const int m0 = blockIdx.y * 128, n0 = blockIdx.x * 128;
    const int dir = m0 >> 13;
    const int r0 = t >> 2, kc0 = (t & 3) * 8;

    const int am0 = (EPI == 3) ? (m0 ^ 8192) : m0;
    const __bf16* Bt = gw.w[dir];
    const __bf16* gA0 = A + (size_t)(am0 + r0) * K + kc0;
    const __bf16* gA1 = gA0 + (size_t)64 * K;
    const __bf16* gB0 = Bt + (size_t)(n0 + r0) * K + kc0;
    const __bf16* gB1 = gB0 + (size_t)64 * K;
    __bf16* dA0 = &As[r0 * 32 + kc0];
    __bf16* dA1 = &As[(r0 + 64) * 32 + kc0];
    __bf16* dB0 = &Bs[r0 * 32 + kc0];
    __bf16* dB1 = &Bs[(r0 + 64) * 32 + kc0];

    const f32x4 zero = {0.f, 0.f, 0.f, 0.f};
    f32x4 acc[4][4];
#pragma unroll
    for (int mi = 0; mi < 4; ++mi)
#pragma unroll
        for (int ni = 0; ni < 4; ++ni) acc[mi][ni] = zero;

    const int nk = K >> 5;
    for (int kt = 0; kt < nk; ++kt) {
        const int ko = kt * 32;
        gload_lds16(gA0 + ko, dA0);
        gload_lds16(gA1 + ko, dA1);
        gload_lds16(gB0 + ko, dB0);
        gload_lds16(gB1 + ko, dB1);
        __syncthreads();
        bf16x8 af[4], bfv[4];
#pragma unroll
        for (int mi = 0; mi < 4; ++mi)
            af[mi] = *(const bf16x8*)(&As[(wr * 64 + mi * 16 + lrow) * 32 + lk * 8]);
#pragma unroll
        for (int ni = 0; ni < 4; ++ni)
            bfv[ni] = *(const bf16x8*)(&Bs[(wc * 64 + ni * 16 + lrow) * 32 + lk * 8]);
#pragma unroll
        for (int mi = 0; mi < 4; ++mi)
#pragma unroll
            for (int ni = 0; ni < 4; ++ni)
                acc[mi][ni] = MFMA16(af[mi], bfv[ni], acc[mi][ni]);
        __syncthreads();
    }

#pragma unroll
    for (int mi = 0; mi < 4; ++mi) {
#pragma unroll
        for (int ni = 0; ni < 4; ++ni) {
            int col = n0 + wc * 64 + ni * 16 + lrow;
            float bv = (EPI == 3 && col >= 1024) ? gw.bias2[dir][col - 1024]
                                                 : gw.bias[dir][col & 1023];
#pragma unroll
            for (int r = 0; r < 4; ++r) {
                int row = m0 + wr * 64 + mi * 16 + lk * 4 + r;
                float v = acc[mi][ni][r] + bv;
                if (EPI == 0) {
                    Cb[(size_t)row * 1024 + col] = (__bf16)v;
                } else if (EPI == 3) {
                    if (col < 1024) {
                        Cb[(size_t)row * 1024 + col] = (__bf16)v;
                    } else {
                        int c2 = col - 1024;
                        int local = row & 8191;
                        int b_ = local >> 9, pos = local & 511;
                        int h_ = c2 >> 6, hd = c2 & 63;
                        Vt[(size_t)dir * 8388608 +
                           (((size_t)(b_ * 16 + h_) * 64 + hd) << 9) + pos] = (__bf16)v;
                    }
                } else {
                    int local = row & 8191;
                    int b_ = local >> 9, s = local & 511;
                    int rh = dir * 512;
                    float rv = resid[((size_t)b_ * 1024 + rh + s) * 1024 + col];
                    Cf[(size_t)row * 1024 + col] = v + rv;
                }
            }
        }
    }
}

// ---------------------------------------------------------------- attention
// Both directions in one launch: grid (512, 8); dir = blockIdx.x>>8.
// Pipelined flash attention: 4 K-tiles of 128 pos, K double-buffered,
// P in own 16KB buffer (wave-private rows). stage(t+1) issued after qk(t),
// drains at tile t+1's __syncthreads -> hides under softmax+PV.
// (256,3): VGPR cap ~170; sc[8]+av+qf fit (84 VGPR) — no spill.
// Swapped QK^T (mfma(K,Q)): lane owns softmax row q = w*16+lrow.
__global__ __launch_bounds__(256, 3) void attn_kernel(const __bf16* __restrict__ Q,
                                                      const __bf16* __restrict__ Kb,
                                                      const __bf16* __restrict__ Vt,
                                                      const float* __restrict__ mask,
                                                      __bf16* __restrict__ att)
{
    __shared__ __align__(16) __bf16 KB[2][128 * 64];  // 2 x 16 KB K tiles (swizzled)
    __shared__ __align__(16) __bf16 Pt[64 * 128];     // 16 KB P tile
    __shared__ __align__(16) float msk[512];
    const int dirbh = blockIdx.x;
    const int dir = dirbh >> 8, bh = dirbh & 255;
    const int b = bh >> 4, h = bh & 15;
    const int mask_half = dir ? 0 : 512;   // p2h (dir0) attends hypothesis
    const int q0 = blockIdx.y * 64;
    const int tid = threadIdx.x, l = tid & 63, w = tid >> 6;
    const int lrow = l & 15, lk = l >> 4;
    const size_t rowbase = (size_t)dir * 8192 + b * 512;

    const __bf16* kbase = Kb + rowbase * 1024 + h * 64;
    const __bf16* vsrc = Vt + (size_t)dir * 8388608 + (size_t)bh * 64 * 512;

    auto stage = [&](int t, int buf) {
        char* dst = (char*)KB[buf];
#pragma unroll
        for (int i = 0; i < 4; ++i) {
            int c = tid + i * 256;
            int pos = c >> 3, gslot = (c & 7) ^ (pos & 7);
            gload_lds16(kbase + (size_t)(t * 128 + pos) * 1024 + gslot * 8, dst + c * 16);
        }
    };

    stage(0, 0);
    for (int i = tid; i < 512; i += 256) msk[i] = mask[b * 1024 + mask_half + i];

    const __bf16* qptr = Q + (rowbase + q0 + w * 16 + lrow) * 1024 + h * 64;
    bf16x8 qf0 = *(const bf16x8*)(qptr + lk * 8);
    bf16x8 qf1 = *(const bf16x8*)(qptr + 32 + lk * 8);

    const f32x4 zero = {0.f, 0.f, 0.f, 0.f};
    f32x4 av[4];
#pragma unroll
    for (int ni = 0; ni < 4; ++ni) av[ni] = zero;
    float m_run = -3e38f, su = 0.f;
    const int psw = lrow & 7;
    char* prowp = (char*)Pt + (w * 16 + lrow) * 256;
    f32x4 sc[8];

#pragma unroll
    for (int t = 0; t < 4; ++t) {
        __syncthreads();   // K[t] staged (vmcnt drained) + all waves past qk(t-1)
        const char* kbuf = (const char*)KB[t & 1];
#pragma unroll
        for (int jj = 0; jj < 8; ++jj) {
            const char* kb = kbuf + (jj * 16 + lrow) * 128;
            bf16x8 k0 = *(const bf16x8*)(kb + ((lk ^ psw) << 4));
            bf16x8 k1 = *(const bf16x8*)(kb + (((lk + 4) ^ psw) << 4));
            f32x4 c = zero;
            c = MFMA16(k0, qf0, c);    // swapped: C[row=k local][col=q local]
            c = MFMA16(k1, qf1, c);
            sc[jj] = c;
        }
        if (t < 3) stage(t + 1, (t + 1) & 1);   // prefetch; hides under softmax+PV

        const int koff = t * 128;
        float mt = -3e38f;
#pragma unroll
        for (int jj = 0; jj < 8; ++jj) {
            f32x4 mv = *(const f32x4*)(&msk[koff + jj * 16 + lk * 4]);
#pragma unroll
            for (int r = 0; r < 4; ++r) {
                float s = sc[jj][r] * 0.125f;   // 1/sqrt(64)
                if (mv[r] == 0.f) s = -1e9f;
                sc[jj][r] = s;
                mt = fmaxf(mt, s);
            }
        }
        mt = fmaxf(mt, __shfl_xor(mt, 16));
        mt = fmaxf(mt, __shfl_xor(mt, 32));
        float m_new = fmaxf(m_run, mt);
        float f = __expf(m_run - m_new);
        float s0 = 0.f, s1 = 0.f;
#pragma unroll
        for (int jj = 0; jj < 8; ++jj) {
            float e0 = __expf(sc[jj][0] - m_new);
            float e1 = __expf(sc[jj][1] - m_new);
            float e2 = __expf(sc[jj][2] - m_new);
            float e3 = __expf(sc[jj][3] - m_new);
            sc[jj][0] = e0; sc[jj][1] = e1; sc[jj][2] = e2; sc[jj][3] = e3;
            s0 += e0 + e1;
            s1 += e2 + e3;
        }
        float ssum = s0 + s1;
        ssum += __shfl_xor(ssum, 16);
        ssum += __shfl_xor(ssum, 32);
        su = su * f + ssum;
        m_run = m_new;
#pragma unroll
        for (int r = 0; r < 4; ++r) {
            float fr = __shfl(f, (l & 48) | (lk * 4 + r));
#pragma unroll
            for (int ni = 0; ni < 4; ++ni) av[ni][r] *= fr;
        }

#pragma unroll
        for (int jj = 0; jj < 8; ++jj) {
            union { __bf16 b[4]; unsigned long long u; } pk;
#pragma unroll
            for (int r = 0; r < 4; ++r) pk.b[r] = (__bf16)sc[jj][r];
            int slot2 = jj * 2 + (lk >> 1);
            *(unsigned long long*)(prowp + (((slot2 ^ psw) << 4) | ((lk & 1) << 3))) = pk.u;
        }
#pragma unroll
        for (int ks = 0; ks < 4; ++ks) {
            bf16x8 pf = *(const bf16x8*)(prowp + (((ks * 4 + lk) ^ psw) << 4));
#pragma unroll
            for (int ni = 0; ni < 4; ++ni) {
                bf16x8 vf = *(const bf16x8*)(&vsrc[(ni * 16 + lrow) * 512 + koff + ks * 32 + lk * 8]);
                av[ni] = MFMA16(pf, vf, av[ni]);
            }
        }
    }

    const float inv = 1.f / su;
#pragma unroll
    for (int r = 0; r < 4; ++r) {
        float ivr = __shfl(inv, (l & 48) | (lk * 4 + r));
        size_t orow = rowbase + q0 + w * 16 + lk * 4 + r;
#pragma unroll
        for (int ni = 0; ni < 4; ++ni)
            att[orow * 1024 + h * 64 + ni * 16 + lrow] = (__bf16)(av[ni][r] * ivr);
    }
}

// ---------------------------------------------------------------- layernorm (16384 rows)
__global__ __launch_bounds__(256) void ln_kernel(const float* __restrict__ X,
                                                 LnW lw,
                                                 __bf16* __restrict__ out)
{
    const int r = blockIdx.x, t = threadIdx.x;
    const int dir = r >> 13;
    const float* g = lw.g[dir];
    const float* bta = lw.b[dir];
    const float* x = X + (size_t)r * 1024;
    f32x4 v = *(const f32x4*)(x + t * 4);
    float s = v[0] + v[1] + v[2] + v[3];
    float q = v[0] * v[0] + v[1] * v[1] + v[2] * v[2] + v[3] * v[3];
#pragma unroll
    for (int d = 1; d < 64; d <<= 1) { s += __shfl_xor(s, d); q += __shfl_xor(q, d); }
    __shared__ float rs[4], rq[4];
    if ((t & 63) == 0) { rs[t >> 6] = s; rq[t >> 6] = q; }
    __syncthreads();
    s = rs[0] + rs[1] + rs[2] + rs[3];
    q = rq[0] + rq[1] + rq[2] + rq[3];
    float mu = s * (1.f / 1024.f);
    float var = q * (1.f / 1024.f) - mu * mu;
    float rstd = rsqrtf(var + 1e-5f);
#pragma unroll
    for (int j = 0; j < 4; ++j) {
        int c = t * 4 + j;
        out[(size_t)r * 1024 + c] = (__bf16)((v[j] - mu) * rstd * g[c] + bta[c]);
    }
}

// ---------------------------------------------------------------- pools
// emb pooling: z = half sel; feats[b][z*1024 + d]
__global__ __launch_bounds__(256) void pool_f32_kernel(const float* __restrict__ X,
                                                       const float* __restrict__ mask,
                                                       float* __restrict__ feats)
{
    const int b = blockIdx.y, d0 = blockIdx.x * 64, half = blockIdx.z * 512;
    const int t = threadIdx.x, d = d0 + (t & 63), sl = t >> 6;
    float acc = 0.f, ms = 0.f;
#pragma unroll 4
    for (int s = sl * 128; s < sl * 128 + 128; ++s) {
        float m = mask[b * 1024 + half + s];
        acc += X[((size_t)b * 1024 + half + s) * 1024 + d] * m;
        ms += m;
    }
    __shared__ float ra[4][64];
    __shared__ float rm[4];
    ra[sl][t & 63] = acc;
    if ((t & 63) == 0) rm[sl] = ms;
    __syncthreads();
    if (t < 64) {
        float a = ra[0][t] + ra[1][t] + ra[2][t] + ra[3][t];
        float m = rm[0] + rm[1] + rm[2] + rm[3];
        feats[b * 4096 + blockIdx.z * 1024 + d0 + t] = a / fmaxf(m, 1e-9f);
    }
}

// ctx pooling merged: z = dir; ctx rows dir*8192 + b*512 + s; mask half = dir*512;
// feats offset 2048 + dir*1024
__global__ __launch_bounds__(256) void pool_bf16_kernel(const __bf16* __restrict__ X,
                                                        const float* __restrict__ mask,
                                                        float* __restrict__ feats)
{
    const int b = blockIdx.y, d0 = blockIdx.x * 64, dir = blockIdx.z;
    const int half = dir * 512;
    const int t = threadIdx.x, d = d0 + (t & 63), sl = t >> 6;
    float acc = 0.f, ms = 0.f;
#pragma unroll 4
    for (int s = sl * 128; s < sl * 128 + 128; ++s) {
        float m = mask[b * 1024 + half + s];
        acc += (float)X[((size_t)dir * 8192 + b * 512 + s) * 1024 + d] * m;
        ms += m;
    }
    __shared__ float ra[4][64];
    __shared__ float rm[4];
    ra[sl][t & 63] = acc;
    if ((t & 63) == 0) rm[sl] = ms;
    __syncthreads();
    if (t < 64) {
        float a = ra[0][t] + ra[1][t] + ra[2][t] + ra[3][t];
        float m = rm[0] + rm[1] + rm[2] + rm[3];
        feats[b * 4096 + 2048 + dir * 1024 + d0 + t] = a / fmaxf(m, 1e-9f);
    }
}

// ---------------------------------------------------------------- small fp32 MLP
__global__ __launch_bounds__(256) void fc_init_kernel(const float* __restrict__ b1,
                                                      const float* __restrict__ b2,
                                                      float* __restrict__ h1,
                                                      float* __restrict__ h2)
{
    int i = blockIdx.x * 256 + threadIdx.x;
    if (i < 16 * 1024) h1[i] = b1[i & 1023];
    else h2[i - 16 * 1024] = b2[(i - 16 * 1024) & 511];
}

template <int CH, int RELU_IN>
__global__ __launch_bounds__(256) void fc_atomic_kernel(const float* __restrict__ in,
                                                        const float* __restrict__ W,
                                                        float* __restrict__ out,
                                                        int IF, int OF)
{
    __shared__ float ins[16 * CH];
    const int t = threadIdx.x;
    const int col = blockIdx.x * 256 + t;
    const int i0 = blockIdx.y * CH;
#pragma unroll
    for (int idx = t; idx < 16 * CH; idx += 256) {
        int b = idx / CH, i = idx % CH;
        float v = in[b * IF + i0 + i];
        if (RELU_IN) v = fmaxf(v, 0.f);
        ins[idx] = v;
    }
    __syncthreads();
    float acc[16];
#pragma unroll
    for (int b = 0; b < 16; ++b) acc[b] = 0.f;
#pragma unroll 4
    for (int i = 0; i < CH; ++i) {
        float wv = W[(size_t)(i0 + i) * OF + col];
#pragma unroll
        for (int b = 0; b < 16; ++b) acc[b] += ins[b * CH + i] * wv;
    }
#pragma unroll
    for (int b = 0; b < 16; ++b) atomicAdd(out + b * OF + col, acc[b]);
}

__global__ __launch_bounds__(64) void mlp3_kernel(const float* __restrict__ h2,
                                                  const float* __restrict__ W3,
                                                  const float* __restrict__ b3,
                                                  float* __restrict__ out)
{
    int b = blockIdx.x, t = threadIdx.x;
    float a0 = 0.f, a1 = 0.f, a2 = 0.f;
    for (int i = t; i < 512; i += 64) {
        float hv = fmaxf(h2[b * 512 + i], 0.f);
        a0 += hv * W3[i * 3 + 0];
        a1 += hv * W3[i * 3 + 1];
        a2 += hv * W3[i * 3 + 2];
    }
#pragma unroll
    for (int d = 1; d < 64; d <<= 1) {
        a0 += __shfl_xor(a0, d);
        a1 += __shfl_xor(a1, d);
        a2 += __shfl_xor(a2, d);
    }
    if (t == 0) {
        out[b * 3 + 0] = a0 + b3[0];
        out[b * 3 + 1] = a1 + b3[1];
        out[b * 3 + 2] = a2 + b3[2];
    }
}

// ---------------------------------------------------------------- launch
extern "C" void kernel_launch(void* const* d_in, const int* in_sizes, int n_in,
                              void* d_out, int out_size, void* d_ws, size_t ws_size,
                              hipStream_t stream)
{
    const float* emb  = (const float*)d_in[0];
    const float* mask = (const float*)d_in[1];
    const float* W1 = (const float*)d_in[22];
    const float* b1 = (const float*)d_in[23];
    const float* W2 = (const float*)d_in[24];
    const float* b2 = (const float*)d_in[25];
    const float* W3 = (const float*)d_in[26];
    const float* b3 = (const float*)d_in[27];

    char* ws = (char*)d_ws;
    constexpr size_t MB = 1ull << 20;
    // Layout (peak ~145 MB):
    __bf16* A     = (__bf16*)(ws);                 // [0,32): premise|hypothesis bf16
    __bf16* Wt    = (__bf16*)(ws + 32 * MB);       // [32,48): 8 x (1024,1024) bf16 W^T
    __bf16* Qb    = (__bf16*)(ws + 48 * MB);       // [48,80): (16384,1024)
    __bf16* Kb    = (__bf16*)(ws + 80 * MB);       // [80,112)
    __bf16* Vt    = (__bf16*)(ws + 112 * MB);      // [112,144): 2 x (B,H,64,512)
    __bf16* attb  = (__bf16*)(ws);                 // [0,32) alias A (dead after KV gemm)
    float*  Of    = (float*) (ws + 48 * MB);       // [48,112) alias Qb+Kb (dead after attn)
    __bf16* ctx   = (__bf16*)(ws);                 // [0,32) alias attb (dead after O gemm)
    float*  feats = (float*) (ws + 144 * MB);      // 256 KB
    float*  h1    = (float*) (ws + 144 * MB + 512 * 1024);
    float*  h2    = (float*) (ws + 145 * MB);

    cast_emb_kernel<<<8192, 256, 0, stream>>>(emb, A);
    WPtrs wp;
    const int widx[8] = {2, 4, 6, 8, 12, 14, 16, 18};   // p2h Wq,Wk,Wv,Wo then h2p
    for (int i = 0; i < 8; ++i) wp.p[i] = (const float*)d_in[widx[i]];
    cast_wt_kernel<<<dim3(32, 32, 8), dim3(32, 8), 0, stream>>>(wp, Wt);

    GemmW gq, gkv, go;
    LnW lw;
    for (int dir = 0; dir < 2; ++dir) {
        const int base = dir ? 12 : 2;
        gq.w[dir]  = Wt + (size_t)(dir * 4 + 0) * 1048576;
        gq.bias[dir]  = (const float*)d_in[base + 1];
        gq.bias2[dir] = nullptr;
        gkv.w[dir] = Wt + (size_t)(dir * 4 + 1) * 1048576;   // Wk|Wv contiguous
        gkv.bias[dir]  = (const float*)d_in[base + 3];
        gkv.bias2[dir] = (const float*)d_in[base + 5];
        go.w[dir]  = Wt + (size_t)(dir * 4 + 3) * 1048576;
        go.bias[dir]  = (const float*)d_in[base + 7];
        go.bias2[dir] = nullptr;
        lw.g[dir] = (const float*)d_in[base + 8];
        lw.b[dir] = (const float*)d_in[base + 9];
    }

    // Q-proj: M=16384, N=1024, direct rows
    gemm_bt<0><<<dim3(8, 128), 256, 0, stream>>>(A, gq, Qb, nullptr, nullptr, nullptr, 1024);
    // KV-proj: M=16384, N=2048, crossed rows (dir0 KV from hypothesis & v.v.)
    gemm_bt<3><<<dim3(16, 128), 256, 0, stream>>>(A, gkv, Kb, Vt, nullptr, nullptr, 1024);
    // attention, both dirs
    attn_kernel<<<dim3(512, 8), 256, 0, stream>>>(Qb, Kb, Vt, mask, attb);
    // O-proj + residual (fp32)
    gemm_bt<2><<<dim3(8, 128), 256, 0, stream>>>(attb, go, nullptr, nullptr, Of, emb, 1024);
    // layernorm -> ctx (bf16)
    ln_kernel<<<16384, 256, 0, stream>>>(Of, lw, ctx);
    // pools
    pool_bf16_kernel<<<dim3(16, 16, 2), 256, 0, stream>>>(ctx, mask, feats);
    pool_f32_kernel<<<dim3(16, 16, 2), 256, 0, stream>>>(emb, mask, feats);

    fc_init_kernel<<<96, 256, 0, stream>>>(b1, b2, h1, h2);
    fc_atomic_kernel<128, 0><<<dim3(4, 32), 256, 0, stream>>>(feats, W1, h1, 4096, 1024);
    fc_atomic_kernel<32, 1><<<dim3(2, 32), 256, 0, stream>>>(h1, W2, h2, 1024, 512);
    mlp3_kernel<<<16, 64, 0, stream>>>(h2, W3, b3, (float*)d_out);
}

// Round 11
// 540.970 us; speedup vs baseline: 1.2390x; 1.0522x over previous
//
#include <hip/hip_runtime.h>
#include <hip/hip_bf16.h>

typedef __attribute__((ext_vector_type(8))) __bf16 bf16x8;
typedef __attribute__((ext_vector_type(4))) float f32x4;
typedef __attribute__((ext_vector_type(4))) int i32x4;
typedef __attribute__((ext_vector_type(4))) unsigned short u16x4;

#define MFMA16(a, b, c) __builtin_amdgcn_mfma_f32_16x16x32_bf16((a), (b), (c), 0, 0, 0)

__device__ __forceinline__ void gload_lds16(const void* g, void* l)
{
    __builtin_amdgcn_global_load_lds(
        (const __attribute__((address_space(1))) unsigned int*)g,
        (__attribute__((address_space(3))) unsigned int*)l, 16, 0, 0);
}

struct LnW { const float* g[2]; const float* b[2]; };

// ---------------------------------------------------------------- casts
// embedded (B,1024,1024) fp32 -> A = [premise 0..8191 | hypothesis 8192..16383] bf16
__global__ __launch_bounds__(256) void cast_emb_kernel(const float* __restrict__ emb,
                                                       __bf16* __restrict__ A)
{
    int i = (blockIdx.x * 256 + threadIdx.x) * 4;
    int r = i >> 10, d = i & 1023;
    size_t src = ((size_t)(r >> 9) * 1024 + (r & 511)) * 1024 + d;
    f32x4 p = *(const f32x4*)(emb + src);
    f32x4 h = *(const f32x4*)(emb + src + 512 * 1024);
    union { __bf16 b[4]; u16x4 u; } cp, ch;
#pragma unroll
    for (int j = 0; j < 4; ++j) { cp.b[j] = (__bf16)p[j]; ch.b[j] = (__bf16)h[j]; }
    *(u16x4*)(A + i) = cp.u;
    *(u16x4*)(A + 8388608 + i) = ch.u;
}

struct WPtrs { const float* p[8]; };
__global__ __launch_bounds__(256) void cast_wt_kernel(WPtrs wp, __bf16* __restrict__ Wt0)
{
    const float* W = wp.p[blockIdx.z];
    __bf16* Wt = Wt0 + (size_t)blockIdx.z * 1048576;
    __shared__ float tile[32][33];
    int n0 = blockIdx.x * 32, k0 = blockIdx.y * 32;
    int tx = threadIdx.x, ty = threadIdx.y;
#pragma unroll
    for (int i = ty; i < 32; i += 8)
        tile[i][tx] = W[(size_t)(k0 + i) * 1024 + n0 + tx];
    __syncthreads();
#pragma unroll
    for (int i = ty; i < 32; i += 8)
        Wt[(size_t)(n0 + i) * 1024 + k0 + tx] = (__bf16)tile[tx][i];
}

// ---------------------------------------------------------------- GEMM (m97 structure)
// Merged 2-direction GEMM, M=16384, dir = m0>>13.
// EPI 5 (QKV): N=3072, seg = n0>>10: 0=Q (A row direct), 1=K, 2=V (A row ^8192).
//   seg0 -> Qb, seg1 -> Kb, seg2 -> Vt V-transposed (dir,B,H,64,512).
// EPI 2 (O): N=1024, direct rows; Cf = v + resid (fp32, emb slice per dir).
struct GArgs {
    const __bf16* w[2];      // EPI5: [Wq;Wk;Wv] 3072x1024 per dir; EPI2: Wo
    const float* bias[6];    // EPI5: [dir*3+seg]; EPI2: [dir*3]
    __bf16* Qb; __bf16* Kb; __bf16* Vt;
    float* Cf; const float* resid;
};
template <int EPI>
__global__ __launch_bounds__(256, 3) void gemm_bt(const __bf16* __restrict__ A, GArgs a)
{
    __shared__ __align__(16) __bf16 As[128 * 32];
    __shared__ __align__(16) __bf16 Bs[128 * 32];
    const int t = threadIdx.x;
    const int l = t & 63, w = t >> 6;
    const int wr = w >> 1, wc = w & 1;
    const int lrow = l & 15, lk = l >> 4;
    const int m0 = blockIdx.y * 128, n0 = blockIdx.x * 128;
    const int dir = m0 >> 13;
    const int seg = (EPI == 5) ? (n0 >> 10) : 0;
    const int r0 = t >> 2, kc0 = (t & 3) * 8;
    const int K = 1024;

    const int am0 = (EPI == 5 && seg != 0) ? (m0 ^ 8192) : m0;
    const __bf16* Bt = a.w[dir];
    const __bf16* gA0 = A + (size_t)(am0 + r0) * K + kc0;
    const __bf16* gA1 = gA0 + (size_t)64 * K;
    const __bf16* gB0 = Bt + (size_t)(n0 + r0) * K + kc0;
    const __bf16* gB1 = gB0 + (size_t)64 * K;
    __bf16* dA0 = &As[r0 * 32 + kc0];
    __bf16* dA1 = &As[(r0 + 64) * 32 + kc0];
    __bf16* dB0 = &Bs[r0 * 32 + kc0];
    __bf16* dB1 = &Bs[(r0 + 64) * 32 + kc0];

    const f32x4 zero = {0.f, 0.f, 0.f, 0.f};
    f32x4 acc[4][4];
#pragma unroll
    for (int mi = 0; mi < 4; ++mi)
#pragma unroll
        for (int ni = 0; ni < 4; ++ni) acc[mi][ni] = zero;

    for (int kt = 0; kt < 32; ++kt) {
        const int ko = kt * 32;
        gload_lds16(gA0 + ko, dA0);
        gload_lds16(gA1 + ko, dA1);
        gload_lds16(gB0 + ko, dB0);
        gload_lds16(gB1 + ko, dB1);
        __syncthreads();
        bf16x8 af[4], bfv[4];
#pragma unroll
        for (int mi = 0; mi < 4; ++mi)
            af[mi] = *(const bf16x8*)(&As[(wr * 64 + mi * 16 + lrow) * 32 + lk * 8]);
#pragma unroll
        for (int ni = 0; ni < 4; ++ni)
            bfv[ni] = *(const bf16x8*)(&Bs[(wc * 64 + ni * 16 + lrow) * 32 + lk * 8]);
#pragma unroll
        for (int mi = 0; mi < 4; ++mi)
#pragma unroll
            for (int ni = 0; ni < 4; ++ni)
                acc[mi][ni] = MFMA16(af[mi], bfv[ni], acc[mi][ni]);
        __syncthreads();
    }

    const float* bsel = a.bias[dir * 3 + seg];
#pragma unroll
    for (int mi = 0; mi < 4; ++mi) {
#pragma unroll
        for (int ni = 0; ni < 4; ++ni) {
            int col = n0 + wc * 64 + ni * 16 + lrow;
            int c2 = col & 1023;
            float bv = bsel[c2];
#pragma unroll
            for (int r = 0; r < 4; ++r) {
                int row = m0 + wr * 64 + mi * 16 + lk * 4 + r;
                float v = acc[mi][ni][r] + bv;
                if (EPI == 5) {
                    if (seg == 0) {
                        a.Qb[(size_t)row * 1024 + c2] = (__bf16)v;
                    } else if (seg == 1) {
                        a.Kb[(size_t)row * 1024 + c2] = (__bf16)v;
                    } else {
                        int local = row & 8191;
                        int b_ = local >> 9, pos = local & 511;
                        int h_ = c2 >> 6, hd = c2 & 63;
                        a.Vt[(size_t)dir * 8388608 +
                             (((size_t)(b_ * 16 + h_) * 64 + hd) << 9) + pos] = (__bf16)v;
                    }
                } else {
                    int local = row & 8191;
                    int b_ = local >> 9, s = local & 511;
                    float rv = a.resid[((size_t)b_ * 1024 + dir * 512 + s) * 1024 + c2];
                    a.Cf[(size_t)row * 1024 + c2] = v + rv;
                }
            }
        }
    }
}

// ---------------------------------------------------------------- attention
// Both directions in one launch: grid (512, 8); dir = blockIdx.x>>8.
// Pipelined flash attention, 4 K-tiles of 128, K double-buffered in LDS,
// P in own 16KB buffer (wave-private rows). V PREFETCHED INTO REGISTERS
// right after QK (16 x bf16x8 = 64 VGPR) so its global latency drains under
// softmax instead of serializing the PV MFMA chain (R10 diagnosis).
// (256,3): cap ~170 VGPR; est. ~150 live — watch VGPR_Count for spill.
__global__ __launch_bounds__(256, 3) void attn_kernel(const __bf16* __restrict__ Q,
                                                      const __bf16* __restrict__ Kb,
                                                      const __bf16* __restrict__ Vt,
                                                      const float* __restrict__ mask,
                                                      __bf16* __restrict__ att)
{
    __shared__ __align__(16) __bf16 KB[2][128 * 64];
    __shared__ __align__(16) __bf16 Pt[64 * 128];
    __shared__ __align__(16) float msk[512];
    const int dirbh = blockIdx.x;
    const int dir = dirbh >> 8, bh = dirbh & 255;
    const int b = bh >> 4, h = bh & 15;
    const int mask_half = dir ? 0 : 512;
    const int q0 = blockIdx.y * 64;
    const int tid = threadIdx.x, l = tid & 63, w = tid >> 6;
    const int lrow = l & 15, lk = l >> 4;
    const size_t rowbase = (size_t)dir * 8192 + b * 512;

    const __bf16* kbase = Kb + rowbase * 1024 + h * 64;
    const __bf16* vsrc = Vt + (size_t)dir * 8388608 + (size_t)bh * 64 * 512;

    auto stage = [&](int t, int buf) {
        char* dst = (char*)KB[buf];
#pragma unroll
        for (int i = 0; i < 4; ++i) {
            int c = tid + i * 256;
            int pos = c >> 3, gslot = (c & 7) ^ (pos & 7);
            gload_lds16(kbase + (size_t)(t * 128 + pos) * 1024 + gslot * 8, dst + c * 16);
        }
    };

    stage(0, 0);
    for (int i = tid; i < 512; i += 256) msk[i] = mask[b * 1024 + mask_half + i];

    const __bf16* qptr = Q + (rowbase + q0 + w * 16 + lrow) * 1024 + h * 64;
    bf16x8 qf0 = *(const bf16x8*)(qptr + lk * 8);
    bf16x8 qf1 = *(const bf16x8*)(qptr + 32 + lk * 8);

    const f32x4 zero = {0.f, 0.f, 0.f, 0.f};
    f32x4 av[4];
#pragma unroll
    for (int ni = 0; ni < 4; ++ni) av[ni] = zero;
    float m_run = -3e38f, su = 0.f;
    const int psw = lrow & 7;
    char* prowp = (char*)Pt + (w * 16 + lrow) * 256;
    f32x4 sc[8];
    bf16x8 vfr[16];

#pragma unroll
    for (int t = 0; t < 4; ++t) {
        __syncthreads();   // K[t] staged (vmcnt drained) + all waves past qk(t-1)
        const char* kbuf = (const char*)KB[t & 1];
#pragma unroll
        for (int jj = 0; jj < 8; ++jj) {
            const char* kb = kbuf + (jj * 16 + lrow) * 128;
            bf16x8 k0 = *(const bf16x8*)(kb + ((lk ^ psw) << 4));
            bf16x8 k1 = *(const bf16x8*)(kb + (((lk + 4) ^ psw) << 4));
            f32x4 c = zero;
            c = MFMA16(k0, qf0, c);    // swapped: C[row=k local][col=q local]
            c = MFMA16(k1, qf1, c);
            sc[jj] = c;
        }
        if (t < 3) stage(t + 1, (t + 1) & 1);   // K prefetch; drains at next barrier

        const int koff = t * 128;
        // V prefetch into registers: 16 independent loads issued before softmax;
        // their latency hides under the softmax VALU phase.
#pragma unroll
        for (int ks = 0; ks < 4; ++ks)
#pragma unroll
            for (int ni = 0; ni < 4; ++ni)
                vfr[ks * 4 + ni] =
                    *(const bf16x8*)(&vsrc[(ni * 16 + lrow) * 512 + koff + ks * 32 + lk * 8]);

        // ---- online softmax
        float mt = -3e38f;
#pragma unroll
        for (int jj = 0; jj < 8; ++jj) {
            f32x4 mv = *(const f32x4*)(&msk[koff + jj * 16 + lk * 4]);
#pragma unroll
            for (int r = 0; r < 4; ++r) {
                float s = sc[jj][r] * 0.125f;   // 1/sqrt(64)
                if (mv[r] == 0.f) s = -1e9f;
                sc[jj][r] = s;
                mt = fmaxf(mt, s);
            }
        }
        mt = fmaxf(mt, __shfl_xor(mt, 16));
        mt = fmaxf(mt, __shfl_xor(mt, 32));
        float m_new = fmaxf(m_run, mt);
        float f = __expf(m_run - m_new);
        float s0 = 0.f, s1 = 0.f;
#pragma unroll
        for (int jj = 0; jj < 8; ++jj) {
            float e0 = __expf(sc[jj][0] - m_new);
            float e1 = __expf(sc[jj][1] - m_new);
            float e2 = __expf(sc[jj][2] - m_new);
            float e3 = __expf(sc[jj][3] - m_new);
            sc[jj][0] = e0; sc[jj][1] = e1; sc[jj][2] = e2; sc[jj][3] = e3;
            s0 += e0 + e1;
            s1 += e2 + e3;
        }
        float ssum = s0 + s1;
        ssum += __shfl_xor(ssum, 16);
        ssum += __shfl_xor(ssum, 32);
        su = su * f + ssum;
        m_run = m_new;
#pragma unroll
        for (int r = 0; r < 4; ++r) {
            float fr = __shfl(f, (l & 48) | (lk * 4 + r));
#pragma unroll
            for (int ni = 0; ni < 4; ++ni) av[ni][r] *= fr;
        }

        // ---- P write (wave-private rows)
#pragma unroll
        for (int jj = 0; jj < 8; ++jj) {
            union { __bf16 b[4]; unsigned long long u; } pk;
#pragma unroll
            for (int r = 0; r < 4; ++r) pk.b[r] = (__bf16)sc[jj][r];
            int slot2 = jj * 2 + (lk >> 1);
            *(unsigned long long*)(prowp + (((slot2 ^ psw) << 4) | ((lk & 1) << 3))) = pk.u;
        }
        // ---- PV (V already in registers)
#pragma unroll
        for (int ks = 0; ks < 4; ++ks) {
            bf16x8 pf = *(const bf16x8*)(prowp + (((ks * 4 + lk) ^ psw) << 4));
#pragma unroll
            for (int ni = 0; ni < 4; ++ni)
                av[ni] = MFMA16(pf, vfr[ks * 4 + ni], av[ni]);
        }
    }

    const float inv = 1.f / su;
#pragma unroll
    for (int r = 0; r < 4; ++r) {
        float ivr = __shfl(inv, (l & 48) | (lk * 4 + r));
        size_t orow = rowbase + q0 + w * 16 + lk * 4 + r;
#pragma unroll
        for (int ni = 0; ni < 4; ++ni)
            att[orow * 1024 + h * 64 + ni * 16 + lrow] = (__bf16)(av[ni][r] * ivr);
    }
}

// ---------------------------------------------------------------- LN stats (mu, rstd per row)
__global__ __launch_bounds__(256) void ln_stats_kernel(const float* __restrict__ X,
                                                       float2* __restrict__ stats)
{
    const int r = blockIdx.x, t = threadIdx.x;
    const float* x = X + (size_t)r * 1024;
    f32x4 v = *(const f32x4*)(x + t * 4);
    float s = v[0] + v[1] + v[2] + v[3];
    float q = v[0] * v[0] + v[1] * v[1] + v[2] * v[2] + v[3] * v[3];
#pragma unroll
    for (int d = 1; d < 64; d <<= 1) { s += __shfl_xor(s, d); q += __shfl_xor(q, d); }
    __shared__ float rs[4], rq[4];
    if ((t & 63) == 0) { rs[t >> 6] = s; rq[t >> 6] = q; }
    __syncthreads();
    if (t == 0) {
        s = rs[0] + rs[1] + rs[2] + rs[3];
        q = rq[0] + rq[1] + rq[2] + rq[3];
        float mu = s * (1.f / 1024.f);
        float var = q * (1.f / 1024.f) - mu * mu;
        stats[r] = make_float2(mu, rsqrtf(var + 1e-5f));
    }
}

// ---------------------------------------------------------------- pools
__global__ __launch_bounds__(256) void pool_f32_kernel(const float* __restrict__ X,
                                                       const float* __restrict__ mask,
                                                       float* __restrict__ feats)
{
    const int b = blockIdx.y, d0 = blockIdx.x * 64, half = blockIdx.z * 512;
    const int t = threadIdx.x, d = d0 + (t & 63), sl = t >> 6;
    float acc = 0.f, ms = 0.f;
#pragma unroll 4
    for (int s = sl * 128; s < sl * 128 + 128; ++s) {
        float m = mask[b * 1024 + half + s];
        acc += X[((size_t)b * 1024 + half + s) * 1024 + d] * m;
        ms += m;
    }
    __shared__ float ra[4][64];
    __shared__ float rm[4];
    ra[sl][t & 63] = acc;
    if ((t & 63) == 0) rm[sl] = ms;
    __syncthreads();
    if (t < 64) {
        float a = ra[0][t] + ra[1][t] + ra[2][t] + ra[3][t];
        float m = rm[0] + rm[1] + rm[2] + rm[3];
        feats[b * 4096 + blockIdx.z * 1024 + d0 + t] = a / fmaxf(m, 1e-9f);
    }
}

// LN fused into ctx-pool: reads Of (fp32) + per-row stats; never materializes ctx.
// feats[b][2048+dir*1024+d] = (g[d]*sum_s m*(x-mu)*rstd + b[d]*sum_s m) / max(sum m,1e-9)
__global__ __launch_bounds__(256) void pool_ln_kernel(const float* __restrict__ Of,
                                                      const float2* __restrict__ stats,
                                                      const float* __restrict__ mask,
                                                      LnW lw,
                                                      float* __restrict__ feats)
{
    const int b = blockIdx.y, d0 = blockIdx.x * 64, dir = blockIdx.z;
    const int half = dir * 512;
    const int t = threadIdx.x, d = d0 + (t & 63), sl = t >> 6;
    float acc = 0.f, ms = 0.f;
#pragma unroll 4
    for (int s = sl * 128; s < sl * 128 + 128; ++s) {
        float m = mask[b * 1024 + half + s];
        int row = dir * 8192 + b * 512 + s;
        float2 st = stats[row];
        float x = Of[(size_t)row * 1024 + d];
        acc += m * (x - st.x) * st.y;
        ms += m;
    }
    __shared__ float ra[4][64];
    __shared__ float rm[4];
    ra[sl][t & 63] = acc;
    if ((t & 63) == 0) rm[sl] = ms;
    __syncthreads();
    if (t < 64) {
        float a = ra[0][t] + ra[1][t] + ra[2][t] + ra[3][t];
        float m = rm[0] + rm[1] + rm[2] + rm[3];
        float g = lw.g[dir][d0 + t], bb = lw.b[dir][d0 + t];
        feats[b * 4096 + 2048 + dir * 1024 + d0 + t] = (g * a + bb * m) / fmaxf(m, 1e-9f);
    }
}

// ---------------------------------------------------------------- small fp32 MLP
__global__ __launch_bounds__(256) void fc_init_kernel(const float* __restrict__ b1,
                                                      const float* __restrict__ b2,
                                                      float* __restrict__ h1,
                                                      float* __restrict__ h2)
{
    int i = blockIdx.x * 256 + threadIdx.x;
    if (i < 16 * 1024) h1[i] = b1[i & 1023];
    else h2[i - 16 * 1024] = b2[(i - 16 * 1024) & 511];
}

template <int CH, int RELU_IN>
__global__ __launch_bounds__(256) void fc_atomic_kernel(const float* __restrict__ in,
                                                        const float* __restrict__ W,
                                                        float* __restrict__ out,
                                                        int IF, int OF)
{
    __shared__ float ins[16 * CH];
    const int t = threadIdx.x;
    const int col = blockIdx.x * 256 + t;
    const int i0 = blockIdx.y * CH;
#pragma unroll
    for (int idx = t; idx < 16 * CH; idx += 256) {
        int b = idx / CH, i = idx % CH;
        float v = in[b * IF + i0 + i];
        if (RELU_IN) v = fmaxf(v, 0.f);
        ins[idx] = v;
    }
    __syncthreads();
    float acc[16];
#pragma unroll
    for (int b = 0; b < 16; ++b) acc[b] = 0.f;
#pragma unroll 4
    for (int i = 0; i < CH; ++i) {
        float wv = W[(size_t)(i0 + i) * OF + col];
#pragma unroll
        for (int b = 0; b < 16; ++b) acc[b] += ins[b * CH + i] * wv;
    }
#pragma unroll
    for (int b = 0; b < 16; ++b) atomicAdd(out + b * OF + col, acc[b]);
}

__global__ __launch_bounds__(64) void mlp3_kernel(const float* __restrict__ h2,
                                                  const float* __restrict__ W3,
                                                  const float* __restrict__ b3,
                                                  float* __restrict__ out)
{
    int b = blockIdx.x, t = threadIdx.x;
    float a0 = 0.f, a1 = 0.f, a2 = 0.f;
    for (int i = t; i < 512; i += 64) {
        float hv = fmaxf(h2[b * 512 + i], 0.f);
        a0 += hv * W3[i * 3 + 0];
        a1 += hv * W3[i * 3 + 1];
        a2 += hv * W3[i * 3 + 2];
    }
#pragma unroll
    for (int d = 1; d < 64; d <<= 1) {
        a0 += __shfl_xor(a0, d);
        a1 += __shfl_xor(a1, d);
        a2 += __shfl_xor(a2, d);
    }
    if (t == 0) {
        out[b * 3 + 0] = a0 + b3[0];
        out[b * 3 + 1] = a1 + b3[1];
        out[b * 3 + 2] = a2 + b3[2];
    }
}

// ---------------------------------------------------------------- launch
extern "C" void kernel_launch(void* const* d_in, const int* in_sizes, int n_in,
                              void* d_out, int out_size, void* d_ws, size_t ws_size,
                              hipStream_t stream)
{
    const float* emb  = (const float*)d_in[0];
    const float* mask = (const float*)d_in[1];
    const float* W1 = (const float*)d_in[22];
    const float* b1 = (const float*)d_in[23];
    const float* W2 = (const float*)d_in[24];
    const float* b2 = (const float*)d_in[25];
    const float* W3 = (const float*)d_in[26];
    const float* b3 = (const float*)d_in[27];

    char* ws = (char*)d_ws;
    constexpr size_t MB = 1ull << 20;
    __bf16* A     = (__bf16*)(ws);                 // [0,32): premise|hypothesis bf16
    __bf16* Wt    = (__bf16*)(ws + 32 * MB);       // [32,48): 8 x W^T bf16
    __bf16* Qb    = (__bf16*)(ws + 48 * MB);       // [48,80)
    __bf16* Kb    = (__bf16*)(ws + 80 * MB);       // [80,112)
    __bf16* Vt    = (__bf16*)(ws + 112 * MB);      // [112,144): 2 x (B,H,64,512)
    __bf16* attb  = (__bf16*)(ws);                 // alias A (dead after QKV gemm)
    float*  Of    = (float*) (ws + 48 * MB);       // alias Qb+Kb (dead after attn)
    float*  feats = (float*) (ws + 144 * MB);      // 256 KB
    float*  h1    = (float*) (ws + 144 * MB + 512 * 1024);
    float*  h2    = (float*) (ws + 145 * MB);
    float2* stats = (float2*)(ws + 146 * MB);      // 128 KB (16384 x {mu,rstd})

    cast_emb_kernel<<<8192, 256, 0, stream>>>(emb, A);
    WPtrs wp;
    const int widx[8] = {2, 4, 6, 8, 12, 14, 16, 18};   // p2h Wq,Wk,Wv,Wo then h2p
    for (int i = 0; i < 8; ++i) wp.p[i] = (const float*)d_in[widx[i]];
    cast_wt_kernel<<<dim3(32, 32, 8), dim3(32, 8), 0, stream>>>(wp, Wt);

    GArgs gqkv = {}, go = {};
    LnW lw;
    for (int dir = 0; dir < 2; ++dir) {
        const int base = dir ? 12 : 2;
        gqkv.w[dir] = Wt + (size_t)(dir * 4) * 1048576;      // [Wq;Wk;Wv] contiguous
        gqkv.bias[dir * 3 + 0] = (const float*)d_in[base + 1];
        gqkv.bias[dir * 3 + 1] = (const float*)d_in[base + 3];
        gqkv.bias[dir * 3 + 2] = (const float*)d_in[base + 5];
        go.w[dir] = Wt + (size_t)(dir * 4 + 3) * 1048576;    // Wo
        go.bias[dir * 3] = (const float*)d_in[base + 7];
        lw.g[dir] = (const float*)d_in[base + 8];
        lw.b[dir] = (const float*)d_in[base + 9];
    }
    gqkv.Qb = Qb; gqkv.Kb = Kb; gqkv.Vt = Vt;
    go.Cf = Of; go.resid = emb;

    // QKV: M=16384, N=3072 (seg 0=Q direct rows, 1=K, 2=V crossed rows)
    gemm_bt<5><<<dim3(24, 128), 256, 0, stream>>>(A, gqkv);
    // attention, both dirs
    attn_kernel<<<dim3(512, 8), 256, 0, stream>>>(Qb, Kb, Vt, mask, attb);
    // O-proj + residual (fp32)
    gemm_bt<2><<<dim3(8, 128), 256, 0, stream>>>(attb, go);
    // LN stats + fused LN-pool (ctx never materialized)
    ln_stats_kernel<<<16384, 256, 0, stream>>>(Of, stats);
    pool_ln_kernel<<<dim3(16, 16, 2), 256, 0, stream>>>(Of, stats, mask, lw, feats);
    pool_f32_kernel<<<dim3(16, 16, 2), 256, 0, stream>>>(emb, mask, feats);

    fc_init_kernel<<<96, 256, 0, stream>>>(b1, b2, h1, h2);
    fc_atomic_kernel<128, 0><<<dim3(4, 32), 256, 0, stream>>>(feats, W1, h1, 4096, 1024);
    fc_atomic_kernel<32, 1><<<dim3(2, 32), 256, 0, stream>>>(h1, W2, h2, 1024, 512);
    mlp3_kernel<<<16, 64, 0, stream>>>(h2, W3, b3, (float*)d_out);
}

// Round 12
// 517.174 us; speedup vs baseline: 1.2961x; 1.0460x over previous
//
#include <hip/hip_runtime.h>
#include <hip/hip_bf16.h>

typedef __attribute__((ext_vector_type(8))) __bf16 bf16x8;
typedef __attribute__((ext_vector_type(4))) float f32x4;
typedef __attribute__((ext_vector_type(4))) int i32x4;
typedef __attribute__((ext_vector_type(4))) unsigned short u16x4;

#define MFMA16(a, b, c) __builtin_amdgcn_mfma_f32_16x16x32_bf16((a), (b), (c), 0, 0, 0)

__device__ __forceinline__ void gload_lds16(const void* g, void* l)
{
    __builtin_amdgcn_global_load_lds(
        (const __attribute__((address_space(1))) unsigned int*)g,
        (__attribute__((address_space(3))) unsigned int*)l, 16, 0, 0);
}

struct LnW { const float* g[2]; const float* b[2]; };

// ---------------------------------------------------------------- casts
// embedded (B,1024,1024) fp32 -> A = [premise 0..8191 | hypothesis 8192..16383] bf16
__global__ __launch_bounds__(256) void cast_emb_kernel(const float* __restrict__ emb,
                                                       __bf16* __restrict__ A)
{
    int i = (blockIdx.x * 256 + threadIdx.x) * 4;
    int r = i >> 10, d = i & 1023;
    size_t src = ((size_t)(r >> 9) * 1024 + (r & 511)) * 1024 + d;
    f32x4 p = *(const f32x4*)(emb + src);
    f32x4 h = *(const f32x4*)(emb + src + 512 * 1024);
    union { __bf16 b[4]; u16x4 u; } cp, ch;
#pragma unroll
    for (int j = 0; j < 4; ++j) { cp.b[j] = (__bf16)p[j]; ch.b[j] = (__bf16)h[j]; }
    *(u16x4*)(A + i) = cp.u;
    *(u16x4*)(A + 8388608 + i) = ch.u;
}

struct WPtrs { const float* p[8]; };
__global__ __launch_bounds__(256) void cast_wt_kernel(WPtrs wp, __bf16* __restrict__ Wt0)
{
    const float* W = wp.p[blockIdx.z];
    __bf16* Wt = Wt0 + (size_t)blockIdx.z * 1048576;
    __shared__ float tile[32][33];
    int n0 = blockIdx.x * 32, k0 = blockIdx.y * 32;
    int tx = threadIdx.x, ty = threadIdx.y;
#pragma unroll
    for (int i = ty; i < 32; i += 8)
        tile[i][tx] = W[(size_t)(k0 + i) * 1024 + n0 + tx];
    __syncthreads();
#pragma unroll
    for (int i = ty; i < 32; i += 8)
        Wt[(size_t)(n0 + i) * 1024 + k0 + tx] = (__bf16)tile[tx][i];
}

// ---------------------------------------------------------------- GEMM (m97 structure)
// Merged 2-direction GEMM, M=16384 (128 m-panels), dir = mblk>>6.
// XCD-locality 1-D grid (nwg = 8*16*NN): x=id&7, r=id>>3, mm=r&15, n=r>>4,
// mblk = x*16+mm. XCD x owns m-panels [16x,16x+16): its 4 MB of A stays
// L2-resident while n sweeps; weights stream once per XCD.
// [R11 counter-diagnosis: grid (n-fast) put XCD = n%8 -> every XCD streamed
//  ALL 32 MB of A -> FETCH 310 MB, kernel ran at traffic rate 2.5 TB/s.]
// EPI 5 (QKV): NN=24, seg = n0>>10: 0=Q (A row direct), 1=K, 2=V (A row ^8192).
// EPI 2 (O):   NN=8, direct rows; Cf = v + resid (fp32).
struct GArgs {
    const __bf16* w[2];
    const float* bias[6];
    __bf16* Qb; __bf16* Kb; __bf16* Vt;
    float* Cf; const float* resid;
};
template <int EPI>
__global__ __launch_bounds__(256, 3) void gemm_bt(const __bf16* __restrict__ A, GArgs a,
                                                  int NN)
{
    __shared__ __align__(16) __bf16 As[128 * 32];
    __shared__ __align__(16) __bf16 Bs[128 * 32];
    const int t = threadIdx.x;
    const int l = t & 63, w = t >> 6;
    const int wr = w >> 1, wc = w & 1;
    const int lrow = l & 15, lk = l >> 4;

    const int id = blockIdx.x;
    const int x = id & 7, rr = id >> 3;
    const int mblk = x * 16 + (rr & 15);
    const int nblk = rr >> 4;          // [0, NN)
    const int m0 = mblk * 128, n0 = nblk * 128;
    const int dir = mblk >> 6;
    const int seg = (EPI == 5) ? (n0 >> 10) : 0;
    const int r0 = t >> 2, kc0 = (t & 3) * 8;
    const int K = 1024;

    const int am0 = (EPI == 5 && seg != 0) ? (m0 ^ 8192) : m0;
    const __bf16* Bt = a.w[dir];
    const __bf16* gA0 = A + (size_t)(am0 + r0) * K + kc0;
    const __bf16* gA1 = gA0 + (size_t)64 * K;
    const __bf16* gB0 = Bt + (size_t)(n0 + r0) * K + kc0;
    const __bf16* gB1 = gB0 + (size_t)64 * K;
    __bf16* dA0 = &As[r0 * 32 + kc0];
    __bf16* dA1 = &As[(r0 + 64) * 32 + kc0];
    __bf16* dB0 = &Bs[r0 * 32 + kc0];
    __bf16* dB1 = &Bs[(r0 + 64) * 32 + kc0];

    const f32x4 zero = {0.f, 0.f, 0.f, 0.f};
    f32x4 acc[4][4];
#pragma unroll
    for (int mi = 0; mi < 4; ++mi)
#pragma unroll
        for (int ni = 0; ni < 4; ++ni) acc[mi][ni] = zero;

    for (int kt = 0; kt < 32; ++kt) {
        const int ko = kt * 32;
        gload_lds16(gA0 + ko, dA0);
        gload_lds16(gA1 + ko, dA1);
        gload_lds16(gB0 + ko, dB0);
        gload_lds16(gB1 + ko, dB1);
        __syncthreads();
        bf16x8 af[4], bfv[4];
#pragma unroll
        for (int mi = 0; mi < 4; ++mi)
            af[mi] = *(const bf16x8*)(&As[(wr * 64 + mi * 16 + lrow) * 32 + lk * 8]);
#pragma unroll
        for (int ni = 0; ni < 4; ++ni)
            bfv[ni] = *(const bf16x8*)(&Bs[(wc * 64 + ni * 16 + lrow) * 32 + lk * 8]);
#pragma unroll
        for (int mi = 0; mi < 4; ++mi)
#pragma unroll
            for (int ni = 0; ni < 4; ++ni)
                acc[mi][ni] = MFMA16(af[mi], bfv[ni], acc[mi][ni]);
        __syncthreads();
    }

    const float* bsel = a.bias[dir * 3 + seg];
#pragma unroll
    for (int mi = 0; mi < 4; ++mi) {
#pragma unroll
        for (int ni = 0; ni < 4; ++ni) {
            int col = n0 + wc * 64 + ni * 16 + lrow;
            int c2 = col & 1023;
            float bv = bsel[c2];
#pragma unroll
            for (int r = 0; r < 4; ++r) {
                int row = m0 + wr * 64 + mi * 16 + lk * 4 + r;
                float v = acc[mi][ni][r] + bv;
                if (EPI == 5) {
                    if (seg == 0) {
                        a.Qb[(size_t)row * 1024 + c2] = (__bf16)v;
                    } else if (seg == 1) {
                        a.Kb[(size_t)row * 1024 + c2] = (__bf16)v;
                    } else {
                        int local = row & 8191;
                        int b_ = local >> 9, pos = local & 511;
                        int h_ = c2 >> 6, hd = c2 & 63;
                        a.Vt[(size_t)dir * 8388608 +
                             (((size_t)(b_ * 16 + h_) * 64 + hd) << 9) + pos] = (__bf16)v;
                    }
                } else {
                    int local = row & 8191;
                    int b_ = local >> 9, s = local & 511;
                    float rv = a.resid[((size_t)b_ * 1024 + dir * 512 + s) * 1024 + c2];
                    a.Cf[(size_t)row * 1024 + c2] = v + rv;
                }
            }
        }
    }
}

// ---------------------------------------------------------------- attention
// Both directions in one launch: grid (512, 8); dir = blockIdx.x>>8.
// Pipelined flash attention, 4 K-tiles of 128, K double-buffered in LDS,
// P in own 16KB buffer (wave-private rows). V prefetched into registers
// right after QK so its global latency drains under softmax (R10 diagnosis;
// R11 confirmed: attn left top-5).
__global__ __launch_bounds__(256, 3) void attn_kernel(const __bf16* __restrict__ Q,
                                                      const __bf16* __restrict__ Kb,
                                                      const __bf16* __restrict__ Vt,
                                                      const float* __restrict__ mask,
                                                      __bf16* __restrict__ att)
{
    __shared__ __align__(16) __bf16 KB[2][128 * 64];
    __shared__ __align__(16) __bf16 Pt[64 * 128];
    __shared__ __align__(16) float msk[512];
    const int dirbh = blockIdx.x;
    const int dir = dirbh >> 8, bh = dirbh & 255;
    const int b = bh >> 4, h = bh & 15;
    const int mask_half = dir ? 0 : 512;
    const int q0 = blockIdx.y * 64;
    const int tid = threadIdx.x, l = tid & 63, w = tid >> 6;
    const int lrow = l & 15, lk = l >> 4;
    const size_t rowbase = (size_t)dir * 8192 + b * 512;

    const __bf16* kbase = Kb + rowbase * 1024 + h * 64;
    const __bf16* vsrc = Vt + (size_t)dir * 8388608 + (size_t)bh * 64 * 512;

    auto stage = [&](int t, int buf) {
        char* dst = (char*)KB[buf];
#pragma unroll
        for (int i = 0; i < 4; ++i) {
            int c = tid + i * 256;
            int pos = c >> 3, gslot = (c & 7) ^ (pos & 7);
            gload_lds16(kbase + (size_t)(t * 128 + pos) * 1024 + gslot * 8, dst + c * 16);
        }
    };

    stage(0, 0);
    for (int i = tid; i < 512; i += 256) msk[i] = mask[b * 1024 + mask_half + i];

    const __bf16* qptr = Q + (rowbase + q0 + w * 16 + lrow) * 1024 + h * 64;
    bf16x8 qf0 = *(const bf16x8*)(qptr + lk * 8);
    bf16x8 qf1 = *(const bf16x8*)(qptr + 32 + lk * 8);

    const f32x4 zero = {0.f, 0.f, 0.f, 0.f};
    f32x4 av[4];
#pragma unroll
    for (int ni = 0; ni < 4; ++ni) av[ni] = zero;
    float m_run = -3e38f, su = 0.f;
    const int psw = lrow & 7;
    char* prowp = (char*)Pt + (w * 16 + lrow) * 256;
    f32x4 sc[8];
    bf16x8 vfr[16];

#pragma unroll
    for (int t = 0; t < 4; ++t) {
        __syncthreads();   // K[t] staged (vmcnt drained) + all waves past qk(t-1)
        const char* kbuf = (const char*)KB[t & 1];
#pragma unroll
        for (int jj = 0; jj < 8; ++jj) {
            const char* kb = kbuf + (jj * 16 + lrow) * 128;
            bf16x8 k0 = *(const bf16x8*)(kb + ((lk ^ psw) << 4));
            bf16x8 k1 = *(const bf16x8*)(kb + (((lk + 4) ^ psw) << 4));
            f32x4 c = zero;
            c = MFMA16(k0, qf0, c);    // swapped: C[row=k local][col=q local]
            c = MFMA16(k1, qf1, c);
            sc[jj] = c;
        }
        if (t < 3) stage(t + 1, (t + 1) & 1);   // K prefetch; drains at next barrier

        const int koff = t * 128;
#pragma unroll
        for (int ks = 0; ks < 4; ++ks)
#pragma unroll
            for (int ni = 0; ni < 4; ++ni)
                vfr[ks * 4 + ni] =
                    *(const bf16x8*)(&vsrc[(ni * 16 + lrow) * 512 + koff + ks * 32 + lk * 8]);

        float mt = -3e38f;
#pragma unroll
        for (int jj = 0; jj < 8; ++jj) {
            f32x4 mv = *(const f32x4*)(&msk[koff + jj * 16 + lk * 4]);
#pragma unroll
            for (int r = 0; r < 4; ++r) {
                float s = sc[jj][r] * 0.125f;   // 1/sqrt(64)
                if (mv[r] == 0.f) s = -1e9f;
                sc[jj][r] = s;
                mt = fmaxf(mt, s);
            }
        }
        mt = fmaxf(mt, __shfl_xor(mt, 16));
        mt = fmaxf(mt, __shfl_xor(mt, 32));
        float m_new = fmaxf(m_run, mt);
        float f = __expf(m_run - m_new);
        float s0 = 0.f, s1 = 0.f;
#pragma unroll
        for (int jj = 0; jj < 8; ++jj) {
            float e0 = __expf(sc[jj][0] - m_new);
            float e1 = __expf(sc[jj][1] - m_new);
            float e2 = __expf(sc[jj][2] - m_new);
            float e3 = __expf(sc[jj][3] - m_new);
            sc[jj][0] = e0; sc[jj][1] = e1; sc[jj][2] = e2; sc[jj][3] = e3;
            s0 += e0 + e1;
            s1 += e2 + e3;
        }
        float ssum = s0 + s1;
        ssum += __shfl_xor(ssum, 16);
        ssum += __shfl_xor(ssum, 32);
        su = su * f + ssum;
        m_run = m_new;
#pragma unroll
        for (int r = 0; r < 4; ++r) {
            float fr = __shfl(f, (l & 48) | (lk * 4 + r));
#pragma unroll
            for (int ni = 0; ni < 4; ++ni) av[ni][r] *= fr;
        }

#pragma unroll
        for (int jj = 0; jj < 8; ++jj) {
            union { __bf16 b[4]; unsigned long long u; } pk;
#pragma unroll
            for (int r = 0; r < 4; ++r) pk.b[r] = (__bf16)sc[jj][r];
            int slot2 = jj * 2 + (lk >> 1);
            *(unsigned long long*)(prowp + (((slot2 ^ psw) << 4) | ((lk & 1) << 3))) = pk.u;
        }
#pragma unroll
        for (int ks = 0; ks < 4; ++ks) {
            bf16x8 pf = *(const bf16x8*)(prowp + (((ks * 4 + lk) ^ psw) << 4));
#pragma unroll
            for (int ni = 0; ni < 4; ++ni)
                av[ni] = MFMA16(pf, vfr[ks * 4 + ni], av[ni]);
        }
    }

    const float inv = 1.f / su;
#pragma unroll
    for (int r = 0; r < 4; ++r) {
        float ivr = __shfl(inv, (l & 48) | (lk * 4 + r));
        size_t orow = rowbase + q0 + w * 16 + lk * 4 + r;
#pragma unroll
        for (int ni = 0; ni < 4; ++ni)
            att[orow * 1024 + h * 64 + ni * 16 + lrow] = (__bf16)(av[ni][r] * ivr);
    }
}

// ---------------------------------------------------------------- LN stats (mu, rstd per row)
__global__ __launch_bounds__(256) void ln_stats_kernel(const float* __restrict__ X,
                                                       float2* __restrict__ stats)
{
    const int r = blockIdx.x, t = threadIdx.x;
    const float* x = X + (size_t)r * 1024;
    f32x4 v = *(const f32x4*)(x + t * 4);
    float s = v[0] + v[1] + v[2] + v[3];
    float q = v[0] * v[0] + v[1] * v[1] + v[2] * v[2] + v[3] * v[3];
#pragma unroll
    for (int d = 1; d < 64; d <<= 1) { s += __shfl_xor(s, d); q += __shfl_xor(q, d); }
    __shared__ float rs[4], rq[4];
    if ((t & 63) == 0) { rs[t >> 6] = s; rq[t >> 6] = q; }
    __syncthreads();
    if (t == 0) {
        s = rs[0] + rs[1] + rs[2] + rs[3];
        q = rq[0] + rq[1] + rq[2] + rq[3];
        float mu = s * (1.f / 1024.f);
        float var = q * (1.f / 1024.f) - mu * mu;
        stats[r] = make_float2(mu, rsqrtf(var + 1e-5f));
    }
}

// ---------------------------------------------------------------- pools
__global__ __launch_bounds__(256) void pool_f32_kernel(const float* __restrict__ X,
                                                       const float* __restrict__ mask,
                                                       float* __restrict__ feats)
{
    const int b = blockIdx.y, d0 = blockIdx.x * 64, half = blockIdx.z * 512;
    const int t = threadIdx.x, d = d0 + (t & 63), sl = t >> 6;
    float acc = 0.f, ms = 0.f;
#pragma unroll 4
    for (int s = sl * 128; s < sl * 128 + 128; ++s) {
        float m = mask[b * 1024 + half + s];
        acc += X[((size_t)b * 1024 + half + s) * 1024 + d] * m;
        ms += m;
    }
    __shared__ float ra[4][64];
    __shared__ float rm[4];
    ra[sl][t & 63] = acc;
    if ((t & 63) == 0) rm[sl] = ms;
    __syncthreads();
    if (t < 64) {
        float a = ra[0][t] + ra[1][t] + ra[2][t] + ra[3][t];
        float m = rm[0] + rm[1] + rm[2] + rm[3];
        feats[b * 4096 + blockIdx.z * 1024 + d0 + t] = a / fmaxf(m, 1e-9f);
    }
}

// LN fused into ctx-pool (ctx never materialized)
__global__ __launch_bounds__(256) void pool_ln_kernel(const float* __restrict__ Of,
                                                      const float2* __restrict__ stats,
                                                      const float* __restrict__ mask,
                                                      LnW lw,
                                                      float* __restrict__ feats)
{
    const int b = blockIdx.y, d0 = blockIdx.x * 64, dir = blockIdx.z;
    const int half = dir * 512;
    const int t = threadIdx.x, d = d0 + (t & 63), sl = t >> 6;
    float acc = 0.f, ms = 0.f;
#pragma unroll 4
    for (int s = sl * 128; s < sl * 128 + 128; ++s) {
        float m = mask[b * 1024 + half + s];
        int row = dir * 8192 + b * 512 + s;
        float2 st = stats[row];
        float x = Of[(size_t)row * 1024 + d];
        acc += m * (x - st.x) * st.y;
        ms += m;
    }
    __shared__ float ra[4][64];
    __shared__ float rm[4];
    ra[sl][t & 63] = acc;
    if ((t & 63) == 0) rm[sl] = ms;
    __syncthreads();
    if (t < 64) {
        float a = ra[0][t] + ra[1][t] + ra[2][t] + ra[3][t];
        float m = rm[0] + rm[1] + rm[2] + rm[3];
        float g = lw.g[dir][d0 + t], bb = lw.b[dir][d0 + t];
        feats[b * 4096 + 2048 + dir * 1024 + d0 + t] = (g * a + bb * m) / fmaxf(m, 1e-9f);
    }
}

// ---------------------------------------------------------------- small fp32 MLP
__global__ __launch_bounds__(256) void fc_init_kernel(const float* __restrict__ b1,
                                                      const float* __restrict__ b2,
                                                      float* __restrict__ h1,
                                                      float* __restrict__ h2)
{
    int i = blockIdx.x * 256 + threadIdx.x;
    if (i < 16 * 1024) h1[i] = b1[i & 1023];
    else h2[i - 16 * 1024] = b2[(i - 16 * 1024) & 511];
}

template <int CH, int RELU_IN>
__global__ __launch_bounds__(256) void fc_atomic_kernel(const float* __restrict__ in,
                                                        const float* __restrict__ W,
                                                        float* __restrict__ out,
                                                        int IF, int OF)
{
    __shared__ float ins[16 * CH];
    const int t = threadIdx.x;
    const int col = blockIdx.x * 256 + t;
    const int i0 = blockIdx.y * CH;
#pragma unroll
    for (int idx = t; idx < 16 * CH; idx += 256) {
        int b = idx / CH, i = idx % CH;
        float v = in[b * IF + i0 + i];
        if (RELU_IN) v = fmaxf(v, 0.f);
        ins[idx] = v;
    }
    __syncthreads();
    float acc[16];
#pragma unroll
    for (int b = 0; b < 16; ++b) acc[b] = 0.f;
#pragma unroll 4
    for (int i = 0; i < CH; ++i) {
        float wv = W[(size_t)(i0 + i) * OF + col];
#pragma unroll
        for (int b = 0; b < 16; ++b) acc[b] += ins[b * CH + i] * wv;
    }
#pragma unroll
    for (int b = 0; b < 16; ++b) atomicAdd(out + b * OF + col, acc[b]);
}

__global__ __launch_bounds__(64) void mlp3_kernel(const float* __restrict__ h2,
                                                  const float* __restrict__ W3,
                                                  const float* __restrict__ b3,
                                                  float* __restrict__ out)
{
    int b = blockIdx.x, t = threadIdx.x;
    float a0 = 0.f, a1 = 0.f, a2 = 0.f;
    for (int i = t; i < 512; i += 64) {
        float hv = fmaxf(h2[b * 512 + i], 0.f);
        a0 += hv * W3[i * 3 + 0];
        a1 += hv * W3[i * 3 + 1];
        a2 += hv * W3[i * 3 + 2];
    }
#pragma unroll
    for (int d = 1; d < 64; d <<= 1) {
        a0 += __shfl_xor(a0, d);
        a1 += __shfl_xor(a1, d);
        a2 += __shfl_xor(a2, d);
    }
    if (t == 0) {
        out[b * 3 + 0] = a0 + b3[0];
        out[b * 3 + 1] = a1 + b3[1];
        out[b * 3 + 2] = a2 + b3[2];
    }
}

// ---------------------------------------------------------------- launch
extern "C" void kernel_launch(void* const* d_in, const int* in_sizes, int n_in,
                              void* d_out, int out_size, void* d_ws, size_t ws_size,
                              hipStream_t stream)
{
    const float* emb  = (const float*)d_in[0];
    const float* mask = (const float*)d_in[1];
    const float* W1 = (const float*)d_in[22];
    const float* b1 = (const float*)d_in[23];
    const float* W2 = (const float*)d_in[24];
    const float* b2 = (const float*)d_in[25];
    const float* W3 = (const float*)d_in[26];
    const float* b3 = (const float*)d_in[27];

    char* ws = (char*)d_ws;
    constexpr size_t MB = 1ull << 20;
    __bf16* A     = (__bf16*)(ws);                 // [0,32): premise|hypothesis bf16
    __bf16* Wt    = (__bf16*)(ws + 32 * MB);       // [32,48): 8 x W^T bf16
    __bf16* Qb    = (__bf16*)(ws + 48 * MB);       // [48,80)
    __bf16* Kb    = (__bf16*)(ws + 80 * MB);       // [80,112)
    __bf16* Vt    = (__bf16*)(ws + 112 * MB);      // [112,144): 2 x (B,H,64,512)
    __bf16* attb  = (__bf16*)(ws);                 // alias A (dead after QKV gemm)
    float*  Of    = (float*) (ws + 48 * MB);       // alias Qb+Kb (dead after attn)
    float*  feats = (float*) (ws + 144 * MB);      // 256 KB
    float*  h1    = (float*) (ws + 144 * MB + 512 * 1024);
    float*  h2    = (float*) (ws + 145 * MB);
    float2* stats = (float2*)(ws + 146 * MB);      // 128 KB

    cast_emb_kernel<<<8192, 256, 0, stream>>>(emb, A);
    WPtrs wp;
    const int widx[8] = {2, 4, 6, 8, 12, 14, 16, 18};   // p2h Wq,Wk,Wv,Wo then h2p
    for (int i = 0; i < 8; ++i) wp.p[i] = (const float*)d_in[widx[i]];
    cast_wt_kernel<<<dim3(32, 32, 8), dim3(32, 8), 0, stream>>>(wp, Wt);

    GArgs gqkv = {}, go = {};
    LnW lw;
    for (int dir = 0; dir < 2; ++dir) {
        const int base = dir ? 12 : 2;
        gqkv.w[dir] = Wt + (size_t)(dir * 4) * 1048576;      // [Wq;Wk;Wv] contiguous
        gqkv.bias[dir * 3 + 0] = (const float*)d_in[base + 1];
        gqkv.bias[dir * 3 + 1] = (const float*)d_in[base + 3];
        gqkv.bias[dir * 3 + 2] = (const float*)d_in[base + 5];
        go.w[dir] = Wt + (size_t)(dir * 4 + 3) * 1048576;    // Wo
        go.bias[dir * 3] = (const float*)d_in[base + 7];
        lw.g[dir] = (const float*)d_in[base + 8];
        lw.b[dir] = (const float*)d_in[base + 9];
    }
    gqkv.Qb = Qb; gqkv.Kb = Kb; gqkv.Vt = Vt;
    go.Cf = Of; go.resid = emb;

    // QKV: 3072 WGs = 8 xcd * 16 m * 24 n  (XCD-locality decode in-kernel)
    gemm_bt<5><<<3072, 256, 0, stream>>>(A, gqkv, 24);
    // attention, both dirs
    attn_kernel<<<dim3(512, 8), 256, 0, stream>>>(Qb, Kb, Vt, mask, attb);
    // O-proj + residual: 1024 WGs = 8 * 16 * 8
    gemm_bt<2><<<1024, 256, 0, stream>>>(attb, go, 8);
    // LN stats + fused LN-pool
    ln_stats_kernel<<<16384, 256, 0, stream>>>(Of, stats);
    pool_ln_kernel<<<dim3(16, 16, 2), 256, 0, stream>>>(Of, stats, mask, lw, feats);
    pool_f32_kernel<<<dim3(16, 16, 2), 256, 0, stream>>>(emb, mask, feats);

    fc_init_kernel<<<96, 256, 0, stream>>>(b1, b2, h1, h2);
    fc_atomic_kernel<128, 0><<<dim3(4, 32), 256, 0, stream>>>(feats, W1, h1, 4096, 1024);
    fc_atomic_kernel<32, 1><<<dim3(2, 32), 256, 0, stream>>>(h1, W2, h2, 1024, 512);
    mlp3_kernel<<<16, 64, 0, stream>>>(h2, W3, b3, (float*)d_out);
}